// Round 1
// baseline (225.509 us; speedup 1.0000x reference)
//
#include <hip/hip_runtime.h>
#include <math.h>

typedef unsigned short u16;
typedef unsigned int u32;
typedef __attribute__((ext_vector_type(4))) float f32x4;
typedef __attribute__((ext_vector_type(8))) short s16x8;

#define GLL16(g, l) __builtin_amdgcn_global_load_lds( \
    (const __attribute__((address_space(1))) void*)(g), \
    (__attribute__((address_space(3))) void*)(l), 16, 0, 0)

__device__ __forceinline__ u16 f2bf(float f) {
  union { float f; u32 u; } v; v.f = f;
  u32 r = v.u + 0x7FFFu + ((v.u >> 16) & 1u);
  return (u16)(r >> 16);
}
__device__ __forceinline__ float bf2f(u16 h) {
  union { u32 u; float f; } v; v.u = ((u32)h) << 16;
  return v.f;
}
// pack two floats to bf16x2 (round-half-up) in one v_perm
__device__ __forceinline__ u32 pk2bf(float lo, float hi) {
  union { float f; u32 u; } a, b; a.f = lo; b.f = hi;
  return __builtin_amdgcn_perm(b.u + 0x8000u, a.u + 0x8000u, 0x07060302u);
}
__device__ __forceinline__ float fexp2(float x) {
#if __has_builtin(__builtin_amdgcn_exp2f)
  return __builtin_amdgcn_exp2f(x);
#else
  return exp2f(x);
#endif
}

// ---------------- cast fp32 -> bf16 (packed) ----------------
__global__ __launch_bounds__(256) void cast_kernel(const float* __restrict__ src,
                                                   u16* __restrict__ dst, int n4) {
  int i = blockIdx.x * 256 + threadIdx.x;
  if (i >= n4) return;
  float4 v = ((const float4*)src)[i];
  uint2 o;
  o.x = (u32)f2bf(v.x) | ((u32)f2bf(v.y) << 16);
  o.y = (u32)f2bf(v.z) | ((u32)f2bf(v.w) << 16);
  ((uint2*)dst)[i] = o;
}

// ---------------- RMSNorm: one block per row of 1024 ----------------
__global__ __launch_bounds__(256) void rmsnorm_kernel(const float* __restrict__ x,
                                                      const float* __restrict__ wgt,
                                                      u16* __restrict__ h) {
  const int row = blockIdx.x, tid = threadIdx.x;
  const float4 v = *(const float4*)&x[(size_t)row * 1024 + tid * 4];
  float ss = v.x * v.x + v.y * v.y + v.z * v.z + v.w * v.w;
  ss += __shfl_xor(ss, 1);  ss += __shfl_xor(ss, 2);  ss += __shfl_xor(ss, 4);
  ss += __shfl_xor(ss, 8);  ss += __shfl_xor(ss, 16); ss += __shfl_xor(ss, 32);
  __shared__ float red[4];
  if ((tid & 63) == 0) red[tid >> 6] = ss;
  __syncthreads();
  const float tot = red[0] + red[1] + red[2] + red[3];
  const float s = rsqrtf(tot * (1.0f / 1024.0f) + 1e-6f);
  const float4 g = *(const float4*)&wgt[tid * 4];
  uint2 o;
  o.x = (u32)f2bf(v.x * s * g.x) | ((u32)f2bf(v.y * s * g.y) << 16);
  o.y = (u32)f2bf(v.z * s * g.z) | ((u32)f2bf(v.w * s * g.w) << 16);
  *(uint2*)&h[(size_t)row * 1024 + tid * 4] = o;
}

// ---------------- GEMM: C(MxN) = A(MxK) * Bt(NxK)^T, bf16 MFMA ----------------
template <int EPI>  // 0: write bf16 C. 1: write fp32 C = acc + resid
__global__ __launch_bounds__(256) void gemm_bt(const u16* __restrict__ A,
                                               const u16* __restrict__ Bt,
                                               u16* __restrict__ Cb,
                                               float* __restrict__ Cf,
                                               const float* __restrict__ resid,
                                               int M, int N, int K) {
  __shared__ __attribute__((aligned(16))) u16 As[128 * 32];
  __shared__ __attribute__((aligned(16))) u16 Bs[128 * 32];
  const int tid = threadIdx.x;
  const int w = tid >> 6, lane = tid & 63;
  const int quad = lane >> 4, l16 = lane & 15;
  const int gm0 = blockIdx.y * 128, gn0 = blockIdx.x * 128;
  const int wm = (w & 1) * 64, wn = (w >> 1) * 64;

  f32x4 acc[4][4] = {};

  for (int k0 = 0; k0 < K; k0 += 32) {
    __syncthreads();
    if (w < 2) {
      #pragma unroll
      for (int i = 0; i < 4; ++i) {
        int sb = (w * 4 + i) * 64;
        int slot = sb + lane;
        int m = slot >> 2, c = (slot & 3) ^ (m & 3);
        GLL16(A + (size_t)(gm0 + m) * K + k0 + c * 8, &As[sb * 8]);
      }
    } else {
      #pragma unroll
      for (int i = 0; i < 4; ++i) {
        int sb = ((w - 2) * 4 + i) * 64;
        int slot = sb + lane;
        int n = slot >> 2, c = (slot & 3) ^ (n & 3);
        GLL16(Bt + (size_t)(gn0 + n) * K + k0 + c * 8, &Bs[sb * 8]);
      }
    }
    __syncthreads();
    s16x8 aF[4], bF[4];
    #pragma unroll
    for (int i = 0; i < 4; ++i) {
      int m = wm + i * 16 + l16;
      aF[i] = *(const s16x8*)&As[(m * 4 + (quad ^ (m & 3))) * 8];
    }
    #pragma unroll
    for (int j = 0; j < 4; ++j) {
      int n = wn + j * 16 + l16;
      bF[j] = *(const s16x8*)&Bs[(n * 4 + (quad ^ (n & 3))) * 8];
    }
    #pragma unroll
    for (int i = 0; i < 4; ++i)
      #pragma unroll
      for (int j = 0; j < 4; ++j)
        acc[i][j] = __builtin_amdgcn_mfma_f32_16x16x32_bf16(aF[i], bF[j], acc[i][j], 0, 0, 0);
  }

  #pragma unroll
  for (int i = 0; i < 4; ++i) {
    int row0 = gm0 + wm + i * 16 + quad * 4;
    #pragma unroll
    for (int j = 0; j < 4; ++j) {
      int col = gn0 + wn + j * 16 + l16;
      #pragma unroll
      for (int r = 0; r < 4; ++r) {
        size_t idx = (size_t)(row0 + r) * N + col;
        if (EPI == 0) Cb[idx] = f2bf(acc[i][j][r]);
        else          Cf[idx] = acc[i][j][r] + resid[idx];
      }
    }
  }
}

// ---------------- RoPE + reorder ----------------
// qkv (4096 x 3072) bf16 -> Qr,Kr (bh,T,64), Vt (bh,64,T)
// Q pre-scaled by 0.125*log2(e) so attention uses exp2 directly.
__global__ __launch_bounds__(256) void rope_kernel(const u16* __restrict__ qkv,
                                                   u16* __restrict__ Qr,
                                                   u16* __restrict__ Kr,
                                                   u16* __restrict__ Vt) {
  const int tt = blockIdx.x, bh = blockIdx.y;
  const int b = bh >> 4, h = bh & 15;
  const int tid = threadIdx.x;
  const float QSCALE = 0.125f * 1.4426950408889634f;

  #pragma unroll
  for (int ii = 0; ii < 8; ++ii) {
    int idx = ii * 256 + tid;      // 64 tokens x 32 pairs
    int tl = idx >> 5, jj = idx & 31;
    int t = tt * 64 + tl;
    size_t mrow = (size_t)(b * 2048 + t) * 3072 + h * 64;
    float q1 = bf2f(qkv[mrow + jj]),        q2 = bf2f(qkv[mrow + 32 + jj]);
    float k1 = bf2f(qkv[mrow + 1024 + jj]), k2 = bf2f(qkv[mrow + 1024 + 32 + jj]);
    float invf = exp2f(-(float)jj * (13.287712379549449f / 32.0f));  // 10000^(-j/32)
    float ang = (float)t * invf;
    float sn, cs;
    sincosf(ang, &sn, &cs);
    size_t orow = (size_t)(bh * 2048 + t) * 64;
    Qr[orow + jj]      = f2bf((q1 * cs - q2 * sn) * QSCALE);
    Qr[orow + 32 + jj] = f2bf((q2 * cs + q1 * sn) * QSCALE);
    Kr[orow + jj]      = f2bf(k1 * cs - k2 * sn);
    Kr[orow + 32 + jj] = f2bf(k2 * cs + k1 * sn);
  }

  // V transpose 64x64 via LDS
  __shared__ __attribute__((aligned(16))) u16 Vl[64][72];
  for (int s = tid; s < 512; s += 256) {
    int r = s >> 3, c8 = (s & 7) * 8;
    *(uint4*)&Vl[r][c8] =
        *(const uint4*)&qkv[(size_t)(b * 2048 + tt * 64 + r) * 3072 + 2048 + h * 64 + c8];
  }
  __syncthreads();
  for (int s = tid; s < 512; s += 256) {
    int d = s >> 3, t8 = (s & 7) * 8;
    u16 tmp[8];
    #pragma unroll
    for (int k = 0; k < 8; ++k) tmp[k] = Vl[t8 + k][d];
    *(uint4*)&Vt[(size_t)(bh * 64 + d) * 2048 + tt * 64 + t8] = *(uint4*)tmp;
  }
}

// ---------------- Flash attention v6: paired q-tiles, 4-wave k-split ----------------
// Block = 256 threads = 4 waves. Each block owns (bh, pair p) and processes
// q-tiles 63-p (heavy) then p (light): total k-tiles = 33 for EVERY block, so
// all 1024 blocks have uniform duration (v5's 2048-block grid was exactly one
// residency with 1..32 k-tiles per block -> occupancy decayed to 19%).
// Wave w handles k-tiles j = w, w+4, ... Exact partial sums (no max shift);
// 4-way combine is a plain add of O and l staged via LDS (slots alias the
// dead per-wave P buffers; barrier-protected).
// NOTE: no min-waves clause -- VGPR working set ~112, 4 waves/SIMD.
__global__ __launch_bounds__(256) void attn_kernel(const u16* __restrict__ Qr,
                                                   const u16* __restrict__ Kr,
                                                   const u16* __restrict__ Vt,
                                                   u16* __restrict__ AO) {
  // smem: per-wave P buffers (4 x 4608 B = 18432 B) during the k-loop;
  // reused as 3 x 8192 B O-combine slots between barriers.
  __shared__ __attribute__((aligned(16))) char smem[24576];
  __shared__ float Ls[3][2][64];
  const int tid = threadIdx.x;
  const int w = tid >> 6, lane = tid & 63;
  const int quad = lane >> 4, l16 = lane & 15;
  const int id = blockIdx.x;
  const int bh = id & 31;                 // id%8 = bh%8 -> per-bh XCD affinity
  const int pr = id >> 5;                 // pair index 0..31
  const int b = bh >> 4, h = bh & 15;
  const size_t qkb = (size_t)bh * (2048 * 64);
  const size_t vtb = (size_t)bh * (64 * 2048);
  u16* Pw = (u16*)smem + w * 2304;

  for (int t = 0; t < 2; ++t) {
    const int qi = t ? pr : 63 - pr;      // heavy tile first
    const int q0 = qi * 32;
    const int jmax = qi >> 1;             // last (diagonal) k-tile index

    // Q B-fragments direct from global: B[n=q(l16)][k=d(quad*8+j)]
    s16x8 bQ[2][2];
    #pragma unroll
    for (int s = 0; s < 2; ++s)
      #pragma unroll
      for (int hf = 0; hf < 2; ++hf)
        bQ[s][hf] = *(const s16x8*)&Qr[qkb + (size_t)(q0 + s * 16 + l16) * 64 + hf * 32 + quad * 8];

    f32x4 O[2][4] = {};
    float l_run[2] = {0.0f, 0.0f};

    auto body = [&](int j, bool masked) {
      // K fragments: A[m=key(l16)][k=d(quad*8+..)] = Kr[j*64+kt*16+l16][d slice]
      s16x8 aK[4][2], aV[4][2];
      #pragma unroll
      for (int kt = 0; kt < 4; ++kt) {
        const u16* kp = &Kr[qkb + (size_t)(j * 64 + kt * 16 + l16) * 64 + quad * 8];
        aK[kt][0] = *(const s16x8*)kp;
        aK[kt][1] = *(const s16x8*)(kp + 32);
      }
      // V fragments: A[m=d(l16)][k=key(quad*8+..)] = Vt[dt*16+l16][j*64 + key slice]
      #pragma unroll
      for (int dt = 0; dt < 4; ++dt) {
        const u16* vp = &Vt[vtb + (size_t)(dt * 16 + l16) * 2048 + j * 64 + quad * 8];
        aV[dt][0] = *(const s16x8*)vp;
        aV[dt][1] = *(const s16x8*)(vp + 32);
      }

      // S^T = K . Q^T  (C: row=key quad*4+r, col=q l16)
      f32x4 S[2][4];
      __builtin_amdgcn_s_setprio(1);
      #pragma unroll
      for (int kt = 0; kt < 4; ++kt)
        #pragma unroll
        for (int s = 0; s < 2; ++s) {
          f32x4 z = {};
          z = __builtin_amdgcn_mfma_f32_16x16x32_bf16(aK[kt][0], bQ[s][0], z, 0, 0, 0);
          S[s][kt] = __builtin_amdgcn_mfma_f32_16x16x32_bf16(aK[kt][1], bQ[s][1], z, 0, 0, 0);
        }
      __builtin_amdgcn_s_setprio(0);

      if (masked) {
        #pragma unroll
        for (int s = 0; s < 2; ++s) {
          int q = q0 + s * 16 + l16;
          #pragma unroll
          for (int kt = 0; kt < 4; ++kt) {
            int key0 = j * 64 + kt * 16 + quad * 4;
            #pragma unroll
            for (int r = 0; r < 4; ++r)
              if (key0 + r > q) S[s][kt][r] = -1e30f;
          }
        }
      }

      // exp2 + rowsum + pack P into this wave's LDS buffer
      #pragma unroll
      for (int s = 0; s < 2; ++s) {
        float sum = 0.0f;
        #pragma unroll
        for (int kt = 0; kt < 4; ++kt) {
          #pragma unroll
          for (int r = 0; r < 4; ++r) {
            float e = fexp2(S[s][kt][r]);
            S[s][kt][r] = e;
            sum += e;
          }
        }
        sum += __shfl_xor(sum, 16);
        sum += __shfl_xor(sum, 32);
        l_run[s] += sum;
        #pragma unroll
        for (int kt = 0; kt < 4; ++kt) {
          uint2 pw;
          pw.x = pk2bf(S[s][kt][0], S[s][kt][1]);
          pw.y = pk2bf(S[s][kt][2], S[s][kt][3]);
          *(uint2*)&Pw[s * 1152 + l16 * 72 + kt * 16 + quad * 4] = pw;
        }
      }

      // O^T += V^T . P^T   (B-frag of P from LDS; DS ops are wave-in-order)
      s16x8 bP[2][2];
      #pragma unroll
      for (int s = 0; s < 2; ++s) {
        bP[s][0] = *(const s16x8*)&Pw[s * 1152 + l16 * 72 + quad * 8];
        bP[s][1] = *(const s16x8*)&Pw[s * 1152 + l16 * 72 + 32 + quad * 8];
      }
      __builtin_amdgcn_s_setprio(1);
      #pragma unroll
      for (int dt = 0; dt < 4; ++dt)
        #pragma unroll
        for (int s = 0; s < 2; ++s) {
          O[s][dt] = __builtin_amdgcn_mfma_f32_16x16x32_bf16(aV[dt][0], bP[s][0], O[s][dt], 0, 0, 0);
          O[s][dt] = __builtin_amdgcn_mfma_f32_16x16x32_bf16(aV[dt][1], bP[s][1], O[s][dt], 0, 0, 0);
        }
      __builtin_amdgcn_s_setprio(0);
    };

    for (int j = w; j <= jmax; j += 4) body(j, j == jmax);

    // ---- 4-way combine: O_tot = sum O_w, l_tot = sum l_w (exact) ----
    __syncthreads();  // all waves done with their k-loops (P buffers now dead)
    if (w) {
      Ls[w - 1][0][lane] = l_run[0];
      Ls[w - 1][1][lane] = l_run[1];
      f32x4* sl = (f32x4*)smem + (w - 1) * 512;
      #pragma unroll
      for (int s = 0; s < 2; ++s)
        #pragma unroll
        for (int dt = 0; dt < 4; ++dt)
          sl[(s * 4 + dt) * 64 + lane] = O[s][dt];
    }
    __syncthreads();
    if (w == 0) {
      f32x4* sl = (f32x4*)smem;
      #pragma unroll
      for (int s = 0; s < 2; ++s) {
        float l_tot = l_run[s] + Ls[0][s][lane] + Ls[1][s][lane] + Ls[2][s][lane];
        float inv = __builtin_amdgcn_rcpf(l_tot);
        int q = q0 + s * 16 + l16;
        #pragma unroll
        for (int dt = 0; dt < 4; ++dt) {
          int off = (s * 4 + dt) * 64 + lane;
          f32x4 o = O[s][dt] + sl[off] + sl[512 + off] + sl[1024 + off];
          uint2 ow;
          ow.x = pk2bf(o[0] * inv, o[1] * inv);
          ow.y = pk2bf(o[2] * inv, o[3] * inv);
          *(uint2*)&AO[(size_t)(b * 2048 + q) * 1024 + h * 64 + dt * 16 + quad * 4] = ow;
        }
      }
    }
    __syncthreads();  // protect smem (slots alias P buffers) before next q-tile
  }
}

// ---------------- launcher ----------------
extern "C" void kernel_launch(void* const* d_in, const int* in_sizes, int n_in,
                              void* d_out, int out_size, void* d_ws, size_t ws_size,
                              hipStream_t stream) {
  const float* x      = (const float*)d_in[0];
  const float* norm_w = (const float*)d_in[1];
  const float* w_qkv  = (const float*)d_in[2];
  const float* w_out  = (const float*)d_in[3];
  float* out = (float*)d_out;

  u16* ws     = (u16*)d_ws;
  u16* wqkv_b = ws;                      // 3 145 728
  u16* wout_b = wqkv_b + 3145728;        // 1 048 576
  u16* h_b    = wout_b + 1048576;        // 4 194 304
  u16* qkv_b  = h_b + 4194304;           // 12 582 912
  u16* Qr     = qkv_b + 12582912;        // 4 194 304
  u16* Kr     = Qr + 4194304;            // 4 194 304
  u16* Vt     = Kr + 4194304;            // 4 194 304
  u16* AO     = Vt + 4194304;            // 4 194 304  (total ~75.5 MB)

  cast_kernel<<<3072, 256, 0, stream>>>(w_qkv, wqkv_b, 786432);
  cast_kernel<<<1024, 256, 0, stream>>>(w_out, wout_b, 262144);
  rmsnorm_kernel<<<4096, 256, 0, stream>>>(x, norm_w, h_b);
  gemm_bt<0><<<dim3(24, 32), 256, 0, stream>>>(h_b, wqkv_b, qkv_b, nullptr, nullptr,
                                               4096, 3072, 1024);
  rope_kernel<<<dim3(32, 32), 256, 0, stream>>>(qkv_b, Qr, Kr, Vt);
  attn_kernel<<<1024, 256, 0, stream>>>(Qr, Kr, Vt, AO);
  gemm_bt<1><<<dim3(8, 32), 256, 0, stream>>>(AO, wout_b, nullptr, out, x,
                                              4096, 1024, 1024);
}

// Round 2
// 196.471 us; speedup vs baseline: 1.1478x; 1.1478x over previous
//
#include <hip/hip_runtime.h>
#include <math.h>

typedef unsigned short u16;
typedef unsigned int u32;
typedef __attribute__((ext_vector_type(4))) float f32x4;
typedef __attribute__((ext_vector_type(8))) short s16x8;

#define GLL16(g, l) __builtin_amdgcn_global_load_lds( \
    (const __attribute__((address_space(1))) void*)(g), \
    (__attribute__((address_space(3))) void*)(l), 16, 0, 0)

__device__ __forceinline__ u16 f2bf(float f) {
  union { float f; u32 u; } v; v.f = f;
  u32 r = v.u + 0x7FFFu + ((v.u >> 16) & 1u);
  return (u16)(r >> 16);
}
__device__ __forceinline__ float bf2f(u16 h) {
  union { u32 u; float f; } v; v.u = ((u32)h) << 16;
  return v.f;
}
// pack two floats to bf16x2 (round-half-up) in one v_perm
__device__ __forceinline__ u32 pk2bf(float lo, float hi) {
  union { float f; u32 u; } a, b; a.f = lo; b.f = hi;
  return __builtin_amdgcn_perm(b.u + 0x8000u, a.u + 0x8000u, 0x07060302u);
}
__device__ __forceinline__ float fexp2(float x) {
#if __has_builtin(__builtin_amdgcn_exp2f)
  return __builtin_amdgcn_exp2f(x);
#else
  return exp2f(x);
#endif
}

// ---------------- cast fp32 -> bf16 (packed) ----------------
__global__ __launch_bounds__(256) void cast_kernel(const float* __restrict__ src,
                                                   u16* __restrict__ dst, int n4) {
  int i = blockIdx.x * 256 + threadIdx.x;
  if (i >= n4) return;
  float4 v = ((const float4*)src)[i];
  uint2 o;
  o.x = (u32)f2bf(v.x) | ((u32)f2bf(v.y) << 16);
  o.y = (u32)f2bf(v.z) | ((u32)f2bf(v.w) << 16);
  ((uint2*)dst)[i] = o;
}

// ---------------- RMSNorm: one block per row of 1024 ----------------
__global__ __launch_bounds__(256) void rmsnorm_kernel(const float* __restrict__ x,
                                                      const float* __restrict__ wgt,
                                                      u16* __restrict__ h) {
  const int row = blockIdx.x, tid = threadIdx.x;
  const float4 v = *(const float4*)&x[(size_t)row * 1024 + tid * 4];
  float ss = v.x * v.x + v.y * v.y + v.z * v.z + v.w * v.w;
  ss += __shfl_xor(ss, 1);  ss += __shfl_xor(ss, 2);  ss += __shfl_xor(ss, 4);
  ss += __shfl_xor(ss, 8);  ss += __shfl_xor(ss, 16); ss += __shfl_xor(ss, 32);
  __shared__ float red[4];
  if ((tid & 63) == 0) red[tid >> 6] = ss;
  __syncthreads();
  const float tot = red[0] + red[1] + red[2] + red[3];
  const float s = rsqrtf(tot * (1.0f / 1024.0f) + 1e-6f);
  const float4 g = *(const float4*)&wgt[tid * 4];
  uint2 o;
  o.x = (u32)f2bf(v.x * s * g.x) | ((u32)f2bf(v.y * s * g.y) << 16);
  o.y = (u32)f2bf(v.z * s * g.z) | ((u32)f2bf(v.w * s * g.w) << 16);
  *(uint2*)&h[(size_t)row * 1024 + tid * 4] = o;
}

// ---------------- GEMM: C(MxN) = A(MxK) * Bt(NxK)^T, bf16 MFMA ----------------
template <int EPI>  // 0: write bf16 C. 1: write fp32 C = acc + resid
__global__ __launch_bounds__(256) void gemm_bt(const u16* __restrict__ A,
                                               const u16* __restrict__ Bt,
                                               u16* __restrict__ Cb,
                                               float* __restrict__ Cf,
                                               const float* __restrict__ resid,
                                               int M, int N, int K) {
  __shared__ __attribute__((aligned(16))) u16 As[128 * 32];
  __shared__ __attribute__((aligned(16))) u16 Bs[128 * 32];
  const int tid = threadIdx.x;
  const int w = tid >> 6, lane = tid & 63;
  const int quad = lane >> 4, l16 = lane & 15;
  const int gm0 = blockIdx.y * 128, gn0 = blockIdx.x * 128;
  const int wm = (w & 1) * 64, wn = (w >> 1) * 64;

  f32x4 acc[4][4] = {};

  for (int k0 = 0; k0 < K; k0 += 32) {
    __syncthreads();
    if (w < 2) {
      #pragma unroll
      for (int i = 0; i < 4; ++i) {
        int sb = (w * 4 + i) * 64;
        int slot = sb + lane;
        int m = slot >> 2, c = (slot & 3) ^ (m & 3);
        GLL16(A + (size_t)(gm0 + m) * K + k0 + c * 8, &As[sb * 8]);
      }
    } else {
      #pragma unroll
      for (int i = 0; i < 4; ++i) {
        int sb = ((w - 2) * 4 + i) * 64;
        int slot = sb + lane;
        int n = slot >> 2, c = (slot & 3) ^ (n & 3);
        GLL16(Bt + (size_t)(gn0 + n) * K + k0 + c * 8, &Bs[sb * 8]);
      }
    }
    __syncthreads();
    s16x8 aF[4], bF[4];
    #pragma unroll
    for (int i = 0; i < 4; ++i) {
      int m = wm + i * 16 + l16;
      aF[i] = *(const s16x8*)&As[(m * 4 + (quad ^ (m & 3))) * 8];
    }
    #pragma unroll
    for (int j = 0; j < 4; ++j) {
      int n = wn + j * 16 + l16;
      bF[j] = *(const s16x8*)&Bs[(n * 4 + (quad ^ (n & 3))) * 8];
    }
    #pragma unroll
    for (int i = 0; i < 4; ++i)
      #pragma unroll
      for (int j = 0; j < 4; ++j)
        acc[i][j] = __builtin_amdgcn_mfma_f32_16x16x32_bf16(aF[i], bF[j], acc[i][j], 0, 0, 0);
  }

  #pragma unroll
  for (int i = 0; i < 4; ++i) {
    int row0 = gm0 + wm + i * 16 + quad * 4;
    #pragma unroll
    for (int j = 0; j < 4; ++j) {
      int col = gn0 + wn + j * 16 + l16;
      #pragma unroll
      for (int r = 0; r < 4; ++r) {
        size_t idx = (size_t)(row0 + r) * N + col;
        if (EPI == 0) Cb[idx] = f2bf(acc[i][j][r]);
        else          Cf[idx] = acc[i][j][r] + resid[idx];
      }
    }
  }
}

// ---------------- RoPE + reorder ----------------
// qkv (4096 x 3072) bf16 -> Qr,Kr (bh,T,64), Vt (bh,64,T)
// Q pre-scaled by 0.125*log2(e) so attention uses exp2 directly.
__global__ __launch_bounds__(256) void rope_kernel(const u16* __restrict__ qkv,
                                                   u16* __restrict__ Qr,
                                                   u16* __restrict__ Kr,
                                                   u16* __restrict__ Vt) {
  const int tt = blockIdx.x, bh = blockIdx.y;
  const int b = bh >> 4, h = bh & 15;
  const int tid = threadIdx.x;
  const float QSCALE = 0.125f * 1.4426950408889634f;

  #pragma unroll
  for (int ii = 0; ii < 8; ++ii) {
    int idx = ii * 256 + tid;      // 64 tokens x 32 pairs
    int tl = idx >> 5, jj = idx & 31;
    int t = tt * 64 + tl;
    size_t mrow = (size_t)(b * 2048 + t) * 3072 + h * 64;
    float q1 = bf2f(qkv[mrow + jj]),        q2 = bf2f(qkv[mrow + 32 + jj]);
    float k1 = bf2f(qkv[mrow + 1024 + jj]), k2 = bf2f(qkv[mrow + 1024 + 32 + jj]);
    float invf = exp2f(-(float)jj * (13.287712379549449f / 32.0f));  // 10000^(-j/32)
    float ang = (float)t * invf;
    float sn, cs;
    sincosf(ang, &sn, &cs);
    size_t orow = (size_t)(bh * 2048 + t) * 64;
    Qr[orow + jj]      = f2bf((q1 * cs - q2 * sn) * QSCALE);
    Qr[orow + 32 + jj] = f2bf((q2 * cs + q1 * sn) * QSCALE);
    Kr[orow + jj]      = f2bf(k1 * cs - k2 * sn);
    Kr[orow + 32 + jj] = f2bf(k2 * cs + k1 * sn);
  }

  // V transpose 64x64 via LDS
  __shared__ __attribute__((aligned(16))) u16 Vl[64][72];
  for (int s = tid; s < 512; s += 256) {
    int r = s >> 3, c8 = (s & 7) * 8;
    *(uint4*)&Vl[r][c8] =
        *(const uint4*)&qkv[(size_t)(b * 2048 + tt * 64 + r) * 3072 + 2048 + h * 64 + c8];
  }
  __syncthreads();
  for (int s = tid; s < 512; s += 256) {
    int d = s >> 3, t8 = (s & 7) * 8;
    u16 tmp[8];
    #pragma unroll
    for (int k = 0; k < 8; ++k) tmp[k] = Vl[t8 + k][d];
    *(uint4*)&Vt[(size_t)(bh * 64 + d) * 2048 + tt * 64 + t8] = *(uint4*)tmp;
  }
}

// ---------------- Flash attention v7: shared LDS K/V staging ----------------
// R1 post-mortem: per-body latency ~8000 cyc = 16 K/V fragment global loads
// SERIALIZED at L2/L3 latency (compiler throttled to VGPR=100 and reused load
// destination registers). Fix: all 4 waves share one k-tile, staged into LDS
// with global_load_lds (zero VGPR, async), double-buffered 2-phase schedule.
// Wave w owns q-rows [q0+32w, q0+32w+32): no cross-wave combine at all.
// K/V tiles are XOR-swizzled via pre-swizzled GLOBAL source (linear LDS dest,
// rule #21); fragment ds_read_b128 then lands 2-way-per-bank (free).
// Grid 512 = 32 bh x 16 qblk; complementary qblk mapping makes each CU's two
// blocks sum to a uniform 34 j-tiles.
__global__ __launch_bounds__(256) void attn_kernel(const u16* __restrict__ Qr,
                                                   const u16* __restrict__ Kr,
                                                   const u16* __restrict__ Vt,
                                                   u16* __restrict__ AO) {
  // [0,16K): Kbuf[2][8192]  [16K,32K): Vbuf[2][8192]  [32K,50K): P[4][4608]
  __shared__ __attribute__((aligned(16))) char smem[51200];
  const int tid = threadIdx.x;
  const int w = tid >> 6, lane = tid & 63;
  const int quad = lane >> 4, l16 = lane & 15;
  const int id = blockIdx.x;
  const int bh = id & 31;                 // id%8 = bh%8 -> per-bh XCD affinity
  const int qhv = id >> 5;                // complementary pairing: qblk(qhv) +
  const int qblk = (qhv < 8) ? (15 - 2 * qhv) : (2 * qhv - 16);  // qblk(qhv+8) = 15
  const int b = bh >> 4, h = bh & 15;
  const size_t qkb = (size_t)bh * (2048 * 64);
  const size_t vtb = (size_t)bh * (64 * 2048);
  const int q0 = qblk * 128;
  const int q0w = q0 + w * 32;            // this wave's 32 q-rows
  const int jmax = 2 * qblk + 1;
  u16* Pw = (u16*)(smem + 32768 + w * 4608);

  // Q B-fragments direct from global: B[n=q(l16)][k=d(quad*8+j)]
  s16x8 bQ[2][2];
  #pragma unroll
  for (int s = 0; s < 2; ++s)
    #pragma unroll
    for (int hf = 0; hf < 2; ++hf)
      bQ[s][hf] = *(const s16x8*)&Qr[qkb + (size_t)(q0w + s * 16 + l16) * 64 + hf * 32 + quad * 8];

  f32x4 O[2][4] = {};
  float l_run[2] = {0.0f, 0.0f};

  // staging lane constants: 1KB issue = 8 rows x 64 cols; swizzle col-group
  // by row&7 at the SOURCE so LDS stays linear for global_load_lds.
  const int srow = lane >> 3;             // row within 8-row issue
  const int scg = (lane & 7) ^ srow;      // pre-swizzled 16B col group

  auto STAGE = [&](int jn, int nxt) {
    if (w < 2) {
      #pragma unroll
      for (int ii = 0; ii < 4; ++ii) {
        int i = w * 4 + ii;               // K issue 0..7 (8 rows each)
        GLL16(Kr + qkb + (size_t)(jn * 64 + i * 8 + srow) * 64 + scg * 8,
              smem + nxt * 8192 + i * 1024);
      }
    } else {
      #pragma unroll
      for (int ii = 0; ii < 4; ++ii) {
        int i = (w - 2) * 4 + ii;         // V issue 0..7 (8 d-rows each)
        GLL16(Vt + vtb + (size_t)(i * 8 + srow) * 2048 + jn * 64 + scg * 8,
              smem + 16384 + nxt * 8192 + i * 1024);
      }
    }
  };

  STAGE(0, 0);
  __syncthreads();   // compiler drains vmcnt before s_barrier -> buf0 ready
  int cur = 0;

  for (int j = 0; j <= jmax; ++j) {
    if (j < jmax) STAGE(j + 1, cur ^ 1);  // prefetch overlaps compute below

    if (j * 64 <= q0w + 31) {             // wave-uniform skip of fully-masked tiles
      const u16* Kb = (const u16*)(smem + cur * 8192);
      const u16* Vb = (const u16*)(smem + 16384 + cur * 8192);
      const bool masked = (j * 64 + 63 > q0w);
      const int rsw = (l16 & 7);          // row&7 for swizzled reads

      // K fragments from LDS: A[m=key(l16)][k=d(quad*8+..)]
      s16x8 aK[4][2];
      #pragma unroll
      for (int kt = 0; kt < 4; ++kt)
        #pragma unroll
        for (int hf = 0; hf < 2; ++hf)
          aK[kt][hf] = *(const s16x8*)&Kb[(kt * 16 + l16) * 64 + (((hf * 4 + quad) ^ rsw) * 8)];

      // S^T = K . Q^T  (C: row=key quad*4+r, col=q l16)
      f32x4 S[2][4];
      __builtin_amdgcn_s_setprio(1);
      #pragma unroll
      for (int kt = 0; kt < 4; ++kt)
        #pragma unroll
        for (int s = 0; s < 2; ++s) {
          f32x4 z = {};
          z = __builtin_amdgcn_mfma_f32_16x16x32_bf16(aK[kt][0], bQ[s][0], z, 0, 0, 0);
          S[s][kt] = __builtin_amdgcn_mfma_f32_16x16x32_bf16(aK[kt][1], bQ[s][1], z, 0, 0, 0);
        }
      __builtin_amdgcn_s_setprio(0);

      if (masked) {
        #pragma unroll
        for (int s = 0; s < 2; ++s) {
          int q = q0w + s * 16 + l16;
          #pragma unroll
          for (int kt = 0; kt < 4; ++kt) {
            int key0 = j * 64 + kt * 16 + quad * 4;
            #pragma unroll
            for (int r = 0; r < 4; ++r)
              if (key0 + r > q) S[s][kt][r] = -1e30f;
          }
        }
      }

      // exp2 + rowsum + pack P into this wave's LDS buffer
      #pragma unroll
      for (int s = 0; s < 2; ++s) {
        float sum = 0.0f;
        #pragma unroll
        for (int kt = 0; kt < 4; ++kt) {
          #pragma unroll
          for (int r = 0; r < 4; ++r) {
            float e = fexp2(S[s][kt][r]);
            S[s][kt][r] = e;
            sum += e;
          }
        }
        sum += __shfl_xor(sum, 16);
        sum += __shfl_xor(sum, 32);
        l_run[s] += sum;
        #pragma unroll
        for (int kt = 0; kt < 4; ++kt) {
          uint2 pw;
          pw.x = pk2bf(S[s][kt][0], S[s][kt][1]);
          pw.y = pk2bf(S[s][kt][2], S[s][kt][3]);
          *(uint2*)&Pw[s * 1152 + l16 * 72 + kt * 16 + quad * 4] = pw;
        }
      }

      // P B-fragments (same-wave DS ops are in-order) and V A-fragments.
      // aV read AFTER softmax so aK/aV never live simultaneously (VGPR cap).
      s16x8 bP[2][2];
      #pragma unroll
      for (int s = 0; s < 2; ++s) {
        bP[s][0] = *(const s16x8*)&Pw[s * 1152 + l16 * 72 + quad * 8];
        bP[s][1] = *(const s16x8*)&Pw[s * 1152 + l16 * 72 + 32 + quad * 8];
      }
      s16x8 aV[4][2];
      #pragma unroll
      for (int dt = 0; dt < 4; ++dt)
        #pragma unroll
        for (int hf = 0; hf < 2; ++hf)
          aV[dt][hf] = *(const s16x8*)&Vb[(dt * 16 + l16) * 64 + (((hf * 4 + quad) ^ rsw) * 8)];

      // O^T += V^T . P^T
      __builtin_amdgcn_s_setprio(1);
      #pragma unroll
      for (int dt = 0; dt < 4; ++dt)
        #pragma unroll
        for (int s = 0; s < 2; ++s) {
          O[s][dt] = __builtin_amdgcn_mfma_f32_16x16x32_bf16(aV[dt][0], bP[s][0], O[s][dt], 0, 0, 0);
          O[s][dt] = __builtin_amdgcn_mfma_f32_16x16x32_bf16(aV[dt][1], bP[s][1], O[s][dt], 0, 0, 0);
        }
      __builtin_amdgcn_s_setprio(0);
    }

    __syncthreads();  // drains prefetch vmcnt + all LDS reads; flip buffers
    cur ^= 1;
  }

  // ---- epilogue: each wave owns its q-rows outright ----
  #pragma unroll
  for (int s = 0; s < 2; ++s) {
    float inv = __builtin_amdgcn_rcpf(l_run[s]);
    int q = q0w + s * 16 + l16;
    #pragma unroll
    for (int dt = 0; dt < 4; ++dt) {
      uint2 ow;
      ow.x = pk2bf(O[s][dt][0] * inv, O[s][dt][1] * inv);
      ow.y = pk2bf(O[s][dt][2] * inv, O[s][dt][3] * inv);
      *(uint2*)&AO[(size_t)(b * 2048 + q) * 1024 + h * 64 + dt * 16 + quad * 4] = ow;
    }
  }
}

// ---------------- launcher ----------------
extern "C" void kernel_launch(void* const* d_in, const int* in_sizes, int n_in,
                              void* d_out, int out_size, void* d_ws, size_t ws_size,
                              hipStream_t stream) {
  const float* x      = (const float*)d_in[0];
  const float* norm_w = (const float*)d_in[1];
  const float* w_qkv  = (const float*)d_in[2];
  const float* w_out  = (const float*)d_in[3];
  float* out = (float*)d_out;

  u16* ws     = (u16*)d_ws;
  u16* wqkv_b = ws;                      // 3 145 728
  u16* wout_b = wqkv_b + 3145728;        // 1 048 576
  u16* h_b    = wout_b + 1048576;        // 4 194 304
  u16* qkv_b  = h_b + 4194304;           // 12 582 912
  u16* Qr     = qkv_b + 12582912;        // 4 194 304
  u16* Kr     = Qr + 4194304;            // 4 194 304
  u16* Vt     = Kr + 4194304;            // 4 194 304
  u16* AO     = Vt + 4194304;            // 4 194 304  (total ~75.5 MB)

  cast_kernel<<<3072, 256, 0, stream>>>(w_qkv, wqkv_b, 786432);
  cast_kernel<<<1024, 256, 0, stream>>>(w_out, wout_b, 262144);
  rmsnorm_kernel<<<4096, 256, 0, stream>>>(x, norm_w, h_b);
  gemm_bt<0><<<dim3(24, 32), 256, 0, stream>>>(h_b, wqkv_b, qkv_b, nullptr, nullptr,
                                               4096, 3072, 1024);
  rope_kernel<<<dim3(32, 32), 256, 0, stream>>>(qkv_b, Qr, Kr, Vt);
  attn_kernel<<<512, 256, 0, stream>>>(Qr, Kr, Vt, AO);
  gemm_bt<1><<<dim3(8, 32), 256, 0, stream>>>(AO, wout_b, nullptr, out, x,
                                              4096, 1024, 1024);
}

// Round 5
// 190.820 us; speedup vs baseline: 1.1818x; 1.0296x over previous
//
#include <hip/hip_runtime.h>
#include <math.h>

typedef unsigned short u16;
typedef unsigned int u32;
typedef __attribute__((ext_vector_type(4))) float f32x4;
typedef __attribute__((ext_vector_type(8))) short s16x8;

#define GLL16(g, l) __builtin_amdgcn_global_load_lds( \
    (const __attribute__((address_space(1))) void*)(g), \
    (__attribute__((address_space(3))) void*)(l), 16, 0, 0)

__device__ __forceinline__ u16 f2bf(float f) {
  union { float f; u32 u; } v; v.f = f;
  u32 r = v.u + 0x7FFFu + ((v.u >> 16) & 1u);
  return (u16)(r >> 16);
}
__device__ __forceinline__ float bf2f(u16 h) {
  union { u32 u; float f; } v; v.u = ((u32)h) << 16;
  return v.f;
}
// pack two floats to bf16x2 (round-half-up) in one v_perm
__device__ __forceinline__ u32 pk2bf(float lo, float hi) {
  union { float f; u32 u; } a, b; a.f = lo; b.f = hi;
  return __builtin_amdgcn_perm(b.u + 0x8000u, a.u + 0x8000u, 0x07060302u);
}
__device__ __forceinline__ float fexp2(float x) {
#if __has_builtin(__builtin_amdgcn_exp2f)
  return __builtin_amdgcn_exp2f(x);
#else
  return exp2f(x);
#endif
}

// ---------------- cast fp32 -> bf16 (packed) ----------------
__global__ __launch_bounds__(256) void cast_kernel(const float* __restrict__ src,
                                                   u16* __restrict__ dst, int n4) {
  int i = blockIdx.x * 256 + threadIdx.x;
  if (i >= n4) return;
  float4 v = ((const float4*)src)[i];
  uint2 o;
  o.x = (u32)f2bf(v.x) | ((u32)f2bf(v.y) << 16);
  o.y = (u32)f2bf(v.z) | ((u32)f2bf(v.w) << 16);
  ((uint2*)dst)[i] = o;
}

// ---------------- RMSNorm: one block per row of 1024 ----------------
__global__ __launch_bounds__(256) void rmsnorm_kernel(const float* __restrict__ x,
                                                      const float* __restrict__ wgt,
                                                      u16* __restrict__ h) {
  const int row = blockIdx.x, tid = threadIdx.x;
  const float4 v = *(const float4*)&x[(size_t)row * 1024 + tid * 4];
  float ss = v.x * v.x + v.y * v.y + v.z * v.z + v.w * v.w;
  ss += __shfl_xor(ss, 1);  ss += __shfl_xor(ss, 2);  ss += __shfl_xor(ss, 4);
  ss += __shfl_xor(ss, 8);  ss += __shfl_xor(ss, 16); ss += __shfl_xor(ss, 32);
  __shared__ float red[4];
  if ((tid & 63) == 0) red[tid >> 6] = ss;
  __syncthreads();
  const float tot = red[0] + red[1] + red[2] + red[3];
  const float s = rsqrtf(tot * (1.0f / 1024.0f) + 1e-6f);
  const float4 g = *(const float4*)&wgt[tid * 4];
  uint2 o;
  o.x = (u32)f2bf(v.x * s * g.x) | ((u32)f2bf(v.y * s * g.y) << 16);
  o.y = (u32)f2bf(v.z * s * g.z) | ((u32)f2bf(v.w * s * g.w) << 16);
  *(uint2*)&h[(size_t)row * 1024 + tid * 4] = o;
}

// ---------------- GEMM: C(MxN) = A(MxK) * Bt(NxK)^T, bf16 MFMA ----------------
template <int EPI>  // 0: write bf16 C. 1: write fp32 C = acc + resid
__global__ __launch_bounds__(256) void gemm_bt(const u16* __restrict__ A,
                                               const u16* __restrict__ Bt,
                                               u16* __restrict__ Cb,
                                               float* __restrict__ Cf,
                                               const float* __restrict__ resid,
                                               int M, int N, int K) {
  __shared__ __attribute__((aligned(16))) u16 As[128 * 32];
  __shared__ __attribute__((aligned(16))) u16 Bs[128 * 32];
  const int tid = threadIdx.x;
  const int w = tid >> 6, lane = tid & 63;
  const int quad = lane >> 4, l16 = lane & 15;
  const int gm0 = blockIdx.y * 128, gn0 = blockIdx.x * 128;
  const int wm = (w & 1) * 64, wn = (w >> 1) * 64;

  f32x4 acc[4][4] = {};

  for (int k0 = 0; k0 < K; k0 += 32) {
    __syncthreads();
    if (w < 2) {
      #pragma unroll
      for (int i = 0; i < 4; ++i) {
        int sb = (w * 4 + i) * 64;
        int slot = sb + lane;
        int m = slot >> 2, c = (slot & 3) ^ (m & 3);
        GLL16(A + (size_t)(gm0 + m) * K + k0 + c * 8, &As[sb * 8]);
      }
    } else {
      #pragma unroll
      for (int i = 0; i < 4; ++i) {
        int sb = ((w - 2) * 4 + i) * 64;
        int slot = sb + lane;
        int n = slot >> 2, c = (slot & 3) ^ (n & 3);
        GLL16(Bt + (size_t)(gn0 + n) * K + k0 + c * 8, &Bs[sb * 8]);
      }
    }
    __syncthreads();
    s16x8 aF[4], bF[4];
    #pragma unroll
    for (int i = 0; i < 4; ++i) {
      int m = wm + i * 16 + l16;
      aF[i] = *(const s16x8*)&As[(m * 4 + (quad ^ (m & 3))) * 8];
    }
    #pragma unroll
    for (int j = 0; j < 4; ++j) {
      int n = wn + j * 16 + l16;
      bF[j] = *(const s16x8*)&Bs[(n * 4 + (quad ^ (n & 3))) * 8];
    }
    #pragma unroll
    for (int i = 0; i < 4; ++i)
      #pragma unroll
      for (int j = 0; j < 4; ++j)
        acc[i][j] = __builtin_amdgcn_mfma_f32_16x16x32_bf16(aF[i], bF[j], acc[i][j], 0, 0, 0);
  }

  #pragma unroll
  for (int i = 0; i < 4; ++i) {
    int row0 = gm0 + wm + i * 16 + quad * 4;
    #pragma unroll
    for (int j = 0; j < 4; ++j) {
      int col = gn0 + wn + j * 16 + l16;
      #pragma unroll
      for (int r = 0; r < 4; ++r) {
        size_t idx = (size_t)(row0 + r) * N + col;
        if (EPI == 0) Cb[idx] = f2bf(acc[i][j][r]);
        else          Cf[idx] = acc[i][j][r] + resid[idx];
      }
    }
  }
}

// ---------------- RoPE + reorder ----------------
// qkv (4096 x 3072) bf16 -> Qr,Kr (bh,T,64), Vt (bh,64,T)
// Q pre-scaled by 0.125*log2(e) so attention uses exp2 directly.
__global__ __launch_bounds__(256) void rope_kernel(const u16* __restrict__ qkv,
                                                   u16* __restrict__ Qr,
                                                   u16* __restrict__ Kr,
                                                   u16* __restrict__ Vt) {
  const int tt = blockIdx.x, bh = blockIdx.y;
  const int b = bh >> 4, h = bh & 15;
  const int tid = threadIdx.x;
  const float QSCALE = 0.125f * 1.4426950408889634f;

  #pragma unroll
  for (int ii = 0; ii < 8; ++ii) {
    int idx = ii * 256 + tid;      // 64 tokens x 32 pairs
    int tl = idx >> 5, jj = idx & 31;
    int t = tt * 64 + tl;
    size_t mrow = (size_t)(b * 2048 + t) * 3072 + h * 64;
    float q1 = bf2f(qkv[mrow + jj]),        q2 = bf2f(qkv[mrow + 32 + jj]);
    float k1 = bf2f(qkv[mrow + 1024 + jj]), k2 = bf2f(qkv[mrow + 1024 + 32 + jj]);
    float invf = exp2f(-(float)jj * (13.287712379549449f / 32.0f));  // 10000^(-j/32)
    float ang = (float)t * invf;
    float sn, cs;
    sincosf(ang, &sn, &cs);
    size_t orow = (size_t)(bh * 2048 + t) * 64;
    Qr[orow + jj]      = f2bf((q1 * cs - q2 * sn) * QSCALE);
    Qr[orow + 32 + jj] = f2bf((q2 * cs + q1 * sn) * QSCALE);
    Kr[orow + jj]      = f2bf(k1 * cs - k2 * sn);
    Kr[orow + 32 + jj] = f2bf(k2 * cs + k1 * sn);
  }

  // V transpose 64x64 via LDS
  __shared__ __attribute__((aligned(16))) u16 Vl[64][72];
  for (int s = tid; s < 512; s += 256) {
    int r = s >> 3, c8 = (s & 7) * 8;
    *(uint4*)&Vl[r][c8] =
        *(const uint4*)&qkv[(size_t)(b * 2048 + tt * 64 + r) * 3072 + 2048 + h * 64 + c8];
  }
  __syncthreads();
  for (int s = tid; s < 512; s += 256) {
    int d = s >> 3, t8 = (s & 7) * 8;
    u16 tmp[8];
    #pragma unroll
    for (int k = 0; k < 8; ++k) tmp[k] = Vl[t8 + k][d];
    *(uint4*)&Vt[(size_t)(bh * 64 + d) * 2048 + tt * 64 + t8] = *(uint4*)tmp;
  }
}

// ---------------- Flash attention v8c: 8-wave uniform blocks, parity k-split ----------------
// Design (R2): grid = 256 uniform blocks (1/CU), 8 waves. Block (bh, c)
// processes q-tiles c and 15-c sequentially: exactly 17 pair-steps everywhere
// -> zero makespan slack. Waves = 4-way q-split x 2-way j-parity: per step,
// parity wp computes tile j=2s+wp from its own staged K/V slot -> 2
// independent waves/SIMD hide latency. Parity partial O/l are exact sums,
// combined once per q-tile through the (dead) staging LDS.
// R3 FIX: shalf was w>>3 (=0) -> rows 32..63 never staged -> NaN.
// R4 FIX: per-wave P stride was 2304 BYTES but the P tile is 2304 u16
// = 4608 BYTES -> waves overlapped neighbors' P (race, nondeterministic
// absmax 0.23..468). P region is now 8 x 4608 B; total LDS 102400 B.
__global__ __launch_bounds__(512) void attn_kernel(const u16* __restrict__ Qr,
                                                   const u16* __restrict__ Kr,
                                                   const u16* __restrict__ Vt,
                                                   u16* __restrict__ AO) {
  // [0,32K): K[par*2+d][8192]  [32K,64K): V[par*2+d][8192]  [64K,100K): P[8][4608]
  __shared__ __attribute__((aligned(16))) char smem[102400];
  const int tid = threadIdx.x;
  const int w = tid >> 6, lane = tid & 63;
  const int wq = w & 3, wp = w >> 2;          // compute roles: q-quarter, j-parity
  const int quad = lane >> 4, l16 = lane & 15;
  const int id = blockIdx.x;
  const int bh = id & 31;                     // id%8 = bh%8 -> per-bh XCD affinity
  const int c  = id >> 5;                     // pair index 0..7
  const int b = bh >> 4, h = bh & 15;
  const size_t qkb = (size_t)bh * (2048 * 64);
  const size_t vtb = (size_t)bh * (64 * 2048);
  u16* Pw = (u16*)(smem + 65536 + w * 4608);

  // staging roles (independent of compute roles): mat = K/V, stp = tile parity,
  // shalf = row half. 8 waves x 4 issues = 32 KB = both tiles of a pair-step.
  const int srow = lane >> 3;                 // row within an 8-row issue
  const int scg  = (lane & 7) ^ srow;         // pre-swizzled 16B col group (rule #21)
  const int smat = w & 1, stp = (w >> 1) & 1, shalf = (w >> 2) & 1;

  auto STAGE = [&](int j0, int d) {
    const int jn = j0 + stp;
    if (smat == 0) {
      #pragma unroll
      for (int ii = 0; ii < 4; ++ii) {
        int i = shalf * 4 + ii;               // 8-row block 0..7
        GLL16(Kr + qkb + (size_t)(jn * 64 + i * 8 + srow) * 64 + scg * 8,
              smem + (stp * 2 + d) * 8192 + i * 1024);
      }
    } else {
      #pragma unroll
      for (int ii = 0; ii < 4; ++ii) {
        int i = shalf * 4 + ii;               // 8 d-rows each
        GLL16(Vt + vtb + (size_t)(i * 8 + srow) * 2048 + jn * 64 + scg * 8,
              smem + 32768 + (stp * 2 + d) * 8192 + i * 1024);
      }
    }
  };

  for (int t = 0; t < 2; ++t) {
    const int qblk = t ? (15 - c) : c;
    const int q0w = qblk * 128 + wq * 32;     // this wave's 32 q-rows
    const int steps = qblk + 1;               // j-tiles = 2*steps (always even)

    // Q B-fragments direct from global: B[n=q(l16)][k=d(quad*8+..)]
    s16x8 bQ[2][2];
    #pragma unroll
    for (int s = 0; s < 2; ++s)
      #pragma unroll
      for (int hf = 0; hf < 2; ++hf)
        bQ[s][hf] = *(const s16x8*)&Qr[qkb + (size_t)(q0w + s * 16 + l16) * 64 + hf * 32 + quad * 8];

    f32x4 O[2][4] = {};
    float l_run[2] = {0.0f, 0.0f};

    STAGE(0, 0);
    __syncthreads();   // compiler drains vmcnt before s_barrier -> dbuf0 ready

    for (int st = 0; st < steps; ++st) {
      const int cur = st & 1;
      if (st + 1 < steps) STAGE(2 * st + 2, cur ^ 1);   // prefetch next pair

      const int j = 2 * st + wp;              // this wave's j-tile
      if (j * 64 <= q0w + 31) {               // wave-uniform skip of fully-masked tiles
        const u16* Kb = (const u16*)(smem + (wp * 2 + cur) * 8192);
        const u16* Vb = (const u16*)(smem + 32768 + (wp * 2 + cur) * 8192);
        const bool masked = (j * 64 + 63 > q0w);
        const int rsw = (l16 & 7);            // row&7 for swizzled reads

        // K fragments from LDS: A[m=key(l16)][k=d(quad*8+..)]
        s16x8 aK[4][2];
        #pragma unroll
        for (int kt = 0; kt < 4; ++kt)
          #pragma unroll
          for (int hf = 0; hf < 2; ++hf)
            aK[kt][hf] = *(const s16x8*)&Kb[(kt * 16 + l16) * 64 + (((hf * 4 + quad) ^ rsw) * 8)];

        // S^T = K . Q^T  (C: row=key quad*4+r, col=q l16)
        f32x4 S[2][4];
        __builtin_amdgcn_s_setprio(1);
        #pragma unroll
        for (int kt = 0; kt < 4; ++kt)
          #pragma unroll
          for (int s = 0; s < 2; ++s) {
            f32x4 z = {};
            z = __builtin_amdgcn_mfma_f32_16x16x32_bf16(aK[kt][0], bQ[s][0], z, 0, 0, 0);
            S[s][kt] = __builtin_amdgcn_mfma_f32_16x16x32_bf16(aK[kt][1], bQ[s][1], z, 0, 0, 0);
          }
        __builtin_amdgcn_s_setprio(0);

        if (masked) {
          #pragma unroll
          for (int s = 0; s < 2; ++s) {
            int q = q0w + s * 16 + l16;
            #pragma unroll
            for (int kt = 0; kt < 4; ++kt) {
              int key0 = j * 64 + kt * 16 + quad * 4;
              #pragma unroll
              for (int r = 0; r < 4; ++r)
                if (key0 + r > q) S[s][kt][r] = -1e30f;
            }
          }
        }

        // exp2 + rowsum + pack P into this wave's LDS buffer
        #pragma unroll
        for (int s = 0; s < 2; ++s) {
          float sum = 0.0f;
          #pragma unroll
          for (int kt = 0; kt < 4; ++kt) {
            #pragma unroll
            for (int r = 0; r < 4; ++r) {
              float e = fexp2(S[s][kt][r]);
              S[s][kt][r] = e;
              sum += e;
            }
          }
          sum += __shfl_xor(sum, 16);
          sum += __shfl_xor(sum, 32);
          l_run[s] += sum;
          #pragma unroll
          for (int kt = 0; kt < 4; ++kt) {
            uint2 pw;
            pw.x = pk2bf(S[s][kt][0], S[s][kt][1]);
            pw.y = pk2bf(S[s][kt][2], S[s][kt][3]);
            *(uint2*)&Pw[s * 1152 + l16 * 72 + kt * 16 + quad * 4] = pw;
          }
        }

        // P B-fragments (same-wave DS ops are in-order); aV read after softmax
        // so aK/aV never live simultaneously (VGPR cap).
        s16x8 bP[2][2];
        #pragma unroll
        for (int s = 0; s < 2; ++s) {
          bP[s][0] = *(const s16x8*)&Pw[s * 1152 + l16 * 72 + quad * 8];
          bP[s][1] = *(const s16x8*)&Pw[s * 1152 + l16 * 72 + 32 + quad * 8];
        }
        s16x8 aV[4][2];
        #pragma unroll
        for (int dt = 0; dt < 4; ++dt)
          #pragma unroll
          for (int hf = 0; hf < 2; ++hf)
            aV[dt][hf] = *(const s16x8*)&Vb[(dt * 16 + l16) * 64 + (((hf * 4 + quad) ^ rsw) * 8)];

        // O^T += V^T . P^T
        __builtin_amdgcn_s_setprio(1);
        #pragma unroll
        for (int dt = 0; dt < 4; ++dt)
          #pragma unroll
          for (int s = 0; s < 2; ++s) {
            O[s][dt] = __builtin_amdgcn_mfma_f32_16x16x32_bf16(aV[dt][0], bP[s][0], O[s][dt], 0, 0, 0);
            O[s][dt] = __builtin_amdgcn_mfma_f32_16x16x32_bf16(aV[dt][1], bP[s][1], O[s][dt], 0, 0, 0);
          }
        __builtin_amdgcn_s_setprio(0);
      }

      __syncthreads();  // drains prefetch vmcnt + all LDS reads; flip dbuf
    }

    // ---- parity combine: O_tot = O_p0 + O_p1, l_tot likewise (exact) ----
    // Staging region (64 KB) is dead here; wq-wave pair uses K-slot wq (8 KB),
    // Lsl lives at the base of the (dead) P region.
    if (wp == 1) {
      float* Lsl = (float*)(smem + 65536 + wq * 512);
      Lsl[lane]      = l_run[0];
      Lsl[64 + lane] = l_run[1];
      f32x4* slot = (f32x4*)smem + wq * 512;
      #pragma unroll
      for (int s = 0; s < 2; ++s)
        #pragma unroll
        for (int dt = 0; dt < 4; ++dt)
          slot[(s * 4 + dt) * 64 + lane] = O[s][dt];
    }
    __syncthreads();
    if (wp == 0) {
      const float* Lsl = (const float*)(smem + 65536 + wq * 512);
      const f32x4* slot = (const f32x4*)smem + wq * 512;
      #pragma unroll
      for (int s = 0; s < 2; ++s) {
        float l_tot = l_run[s] + Lsl[s * 64 + lane];
        float inv = __builtin_amdgcn_rcpf(l_tot);
        int q = q0w + s * 16 + l16;
        #pragma unroll
        for (int dt = 0; dt < 4; ++dt) {
          f32x4 o = O[s][dt] + slot[(s * 4 + dt) * 64 + lane];
          uint2 ow;
          ow.x = pk2bf(o[0] * inv, o[1] * inv);
          ow.y = pk2bf(o[2] * inv, o[3] * inv);
          *(uint2*)&AO[(size_t)(b * 2048 + q) * 1024 + h * 64 + dt * 16 + quad * 4] = ow;
        }
      }
    }
    __syncthreads();  // protect staging region before next tile's STAGE
  }
}

// ---------------- launcher ----------------
extern "C" void kernel_launch(void* const* d_in, const int* in_sizes, int n_in,
                              void* d_out, int out_size, void* d_ws, size_t ws_size,
                              hipStream_t stream) {
  const float* x      = (const float*)d_in[0];
  const float* norm_w = (const float*)d_in[1];
  const float* w_qkv  = (const float*)d_in[2];
  const float* w_out  = (const float*)d_in[3];
  float* out = (float*)d_out;

  u16* ws     = (u16*)d_ws;
  u16* wqkv_b = ws;                      // 3 145 728
  u16* wout_b = wqkv_b + 3145728;        // 1 048 576
  u16* h_b    = wout_b + 1048576;        // 4 194 304
  u16* qkv_b  = h_b + 4194304;           // 12 582 912
  u16* Qr     = qkv_b + 12582912;        // 4 194 304
  u16* Kr     = Qr + 4194304;            // 4 194 304
  u16* Vt     = Kr + 4194304;            // 4 194 304
  u16* AO     = Vt + 4194304;            // 4 194 304  (total ~75.5 MB)

  cast_kernel<<<3072, 256, 0, stream>>>(w_qkv, wqkv_b, 786432);
  cast_kernel<<<1024, 256, 0, stream>>>(w_out, wout_b, 262144);
  rmsnorm_kernel<<<4096, 256, 0, stream>>>(x, norm_w, h_b);
  gemm_bt<0><<<dim3(24, 32), 256, 0, stream>>>(h_b, wqkv_b, qkv_b, nullptr, nullptr,
                                               4096, 3072, 1024);
  rope_kernel<<<dim3(32, 32), 256, 0, stream>>>(qkv_b, Qr, Kr, Vt);
  attn_kernel<<<256, 512, 0, stream>>>(Qr, Kr, Vt, AO);
  gemm_bt<1><<<dim3(8, 32), 256, 0, stream>>>(AO, wout_b, nullptr, out, x,
                                              4096, 1024, 1024);
}

// Round 6
// 186.044 us; speedup vs baseline: 1.2121x; 1.0257x over previous
//
#include <hip/hip_runtime.h>
#include <math.h>

typedef unsigned short u16;
typedef unsigned int u32;
typedef __attribute__((ext_vector_type(4))) float f32x4;
typedef __attribute__((ext_vector_type(8))) short s16x8;

#define GLL16(g, l) __builtin_amdgcn_global_load_lds( \
    (const __attribute__((address_space(1))) void*)(g), \
    (__attribute__((address_space(3))) void*)(l), 16, 0, 0)

#define MFMA16(a, b, c) __builtin_amdgcn_mfma_f32_16x16x32_bf16(a, b, c, 0, 0, 0)

__device__ __forceinline__ u16 f2bf(float f) {
  union { float f; u32 u; } v; v.f = f;
  u32 r = v.u + 0x7FFFu + ((v.u >> 16) & 1u);
  return (u16)(r >> 16);
}
__device__ __forceinline__ float bf2f(u16 h) {
  union { u32 u; float f; } v; v.u = ((u32)h) << 16;
  return v.f;
}
// pack two floats to bf16x2 (round-half-up) in one v_perm
__device__ __forceinline__ u32 pk2bf(float lo, float hi) {
  union { float f; u32 u; } a, b; a.f = lo; b.f = hi;
  return __builtin_amdgcn_perm(b.u + 0x8000u, a.u + 0x8000u, 0x07060302u);
}
__device__ __forceinline__ float fexp2(float x) {
#if __has_builtin(__builtin_amdgcn_exp2f)
  return __builtin_amdgcn_exp2f(x);
#else
  return exp2f(x);
#endif
}

// ---------------- fused prep: rmsnorm + both weight casts (1 launch, was 3) ----
__global__ __launch_bounds__(256) void prep_kernel(const float* __restrict__ x,
                                                   const float* __restrict__ wgt,
                                                   const float* __restrict__ w_qkv,
                                                   const float* __restrict__ w_out,
                                                   u16* __restrict__ h,
                                                   u16* __restrict__ wqkv_b,
                                                   u16* __restrict__ wout_b) {
  __shared__ float red[4];
  const int bid = blockIdx.x, tid = threadIdx.x;
  if (bid < 4096) {
    // RMSNorm row
    const int row = bid;
    const float4 v = *(const float4*)&x[(size_t)row * 1024 + tid * 4];
    float ss = v.x * v.x + v.y * v.y + v.z * v.z + v.w * v.w;
    ss += __shfl_xor(ss, 1);  ss += __shfl_xor(ss, 2);  ss += __shfl_xor(ss, 4);
    ss += __shfl_xor(ss, 8);  ss += __shfl_xor(ss, 16); ss += __shfl_xor(ss, 32);
    if ((tid & 63) == 0) red[tid >> 6] = ss;
    __syncthreads();
    const float tot = red[0] + red[1] + red[2] + red[3];
    const float s = rsqrtf(tot * (1.0f / 1024.0f) + 1e-6f);
    const float4 g = *(const float4*)&wgt[tid * 4];
    uint2 o;
    o.x = (u32)f2bf(v.x * s * g.x) | ((u32)f2bf(v.y * s * g.y) << 16);
    o.y = (u32)f2bf(v.z * s * g.z) | ((u32)f2bf(v.w * s * g.w) << 16);
    *(uint2*)&h[(size_t)row * 1024 + tid * 4] = o;
  } else if (bid < 7168) {
    int i = (bid - 4096) * 256 + tid;          // 786432 float4 of w_qkv
    float4 v = ((const float4*)w_qkv)[i];
    uint2 o;
    o.x = (u32)f2bf(v.x) | ((u32)f2bf(v.y) << 16);
    o.y = (u32)f2bf(v.z) | ((u32)f2bf(v.w) << 16);
    ((uint2*)wqkv_b)[i] = o;
  } else {
    int i = (bid - 7168) * 256 + tid;          // 262144 float4 of w_out
    float4 v = ((const float4*)w_out)[i];
    uint2 o;
    o.x = (u32)f2bf(v.x) | ((u32)f2bf(v.y) << 16);
    o.y = (u32)f2bf(v.z) | ((u32)f2bf(v.w) << 16);
    ((uint2*)wout_b)[i] = o;
  }
}

// ---------------- GEMM 128^2 (kept for out-proj): C = A * Bt^T ----------------
template <int EPI>  // 0: write bf16 C. 1: write fp32 C = acc + resid
__global__ __launch_bounds__(256) void gemm_bt(const u16* __restrict__ A,
                                               const u16* __restrict__ Bt,
                                               u16* __restrict__ Cb,
                                               float* __restrict__ Cf,
                                               const float* __restrict__ resid,
                                               int M, int N, int K) {
  __shared__ __attribute__((aligned(16))) u16 As[128 * 32];
  __shared__ __attribute__((aligned(16))) u16 Bs[128 * 32];
  const int tid = threadIdx.x;
  const int w = tid >> 6, lane = tid & 63;
  const int quad = lane >> 4, l16 = lane & 15;
  const int gm0 = blockIdx.y * 128, gn0 = blockIdx.x * 128;
  const int wm = (w & 1) * 64, wn = (w >> 1) * 64;

  f32x4 acc[4][4] = {};

  for (int k0 = 0; k0 < K; k0 += 32) {
    __syncthreads();
    if (w < 2) {
      #pragma unroll
      for (int i = 0; i < 4; ++i) {
        int sb = (w * 4 + i) * 64;
        int slot = sb + lane;
        int m = slot >> 2, c = (slot & 3) ^ (m & 3);
        GLL16(A + (size_t)(gm0 + m) * K + k0 + c * 8, &As[sb * 8]);
      }
    } else {
      #pragma unroll
      for (int i = 0; i < 4; ++i) {
        int sb = ((w - 2) * 4 + i) * 64;
        int slot = sb + lane;
        int n = slot >> 2, c = (slot & 3) ^ (n & 3);
        GLL16(Bt + (size_t)(gn0 + n) * K + k0 + c * 8, &Bs[sb * 8]);
      }
    }
    __syncthreads();
    s16x8 aF[4], bF[4];
    #pragma unroll
    for (int i = 0; i < 4; ++i) {
      int m = wm + i * 16 + l16;
      aF[i] = *(const s16x8*)&As[(m * 4 + (quad ^ (m & 3))) * 8];
    }
    #pragma unroll
    for (int j = 0; j < 4; ++j) {
      int n = wn + j * 16 + l16;
      bF[j] = *(const s16x8*)&Bs[(n * 4 + (quad ^ (n & 3))) * 8];
    }
    #pragma unroll
    for (int i = 0; i < 4; ++i)
      #pragma unroll
      for (int j = 0; j < 4; ++j)
        acc[i][j] = MFMA16(aF[i], bF[j], acc[i][j]);
  }

  #pragma unroll
  for (int i = 0; i < 4; ++i) {
    int row0 = gm0 + wm + i * 16 + quad * 4;
    #pragma unroll
    for (int j = 0; j < 4; ++j) {
      int col = gn0 + wn + j * 16 + l16;
      #pragma unroll
      for (int r = 0; r < 4; ++r) {
        size_t idx = (size_t)(row0 + r) * N + col;
        if (EPI == 0) Cb[idx] = f2bf(acc[i][j][r]);
        else          Cf[idx] = acc[i][j][r] + resid[idx];
      }
    }
  }
}

// ---------------- GEMM 256^2 8-phase (QKV matmul, M=4096 N=3072 K=1024) -------
// T2+T3+T4+T5 structure (guide 5.5): 512 thr / 8 waves (2M x 4N), per-wave
// 128x64 out (acc[8][4]), BK=64, LDS = 2buf x (A 32K + B 32K) = 128 KB,
// 1 block/CU. Per K-tile: 4 phases x {ds_read subtile || stage 1 half-tile ||
// 16 MFMA}, raw s_barrier + asm waits (no compiler vmcnt(0) drain).
// Staging schedule (derived): at tile kt: p0->A0(kt+1), p1->A1(kt+1) [other
// buffer, always safe], p2->B0(kt+2), p3->B1(kt+2) [same buffer; B(kt) reads
// all complete after p1's barrier]. Boundary wait vmcnt(4): allows only the 4
// newest loads (B(kt+2)) outstanding => all of tile kt+1 has landed.
// kt=14 uses vmcnt(0) (guards change the in-flight count there).
__global__ __launch_bounds__(512) void gemm256(const u16* __restrict__ A,
                                               const u16* __restrict__ Bt,
                                               u16* __restrict__ Cb) {
  __shared__ __attribute__((aligned(16))) char smem[131072];
  const int tid = threadIdx.x;
  const int w = tid >> 6, lane = tid & 63;
  const int quad = lane >> 4, l16 = lane & 15;
  const int wr = w >> 2, wc = w & 3;
  const int rsw = l16 & 7;
  const int id = blockIdx.x;
  const int sw = (id & 7) * 24 + (id >> 3);    // XCD swizzle, 192 = 8 x 24
  const int by = sw / 12, bx = sw - by * 12;
  const int gm0 = by * 256, gn0 = bx * 256;
  const int scg = (lane & 7) ^ (lane >> 3);    // pre-swizzled src col-group

  // part: 0=A half0, 1=A half1, 2=B half0, 3=B half1 (half = 128 rows)
  auto STAGE_HALF = [&](int kt, int part) {
    const int sb = (kt & 1) * 65536 + (part >> 1) * 32768 + (part & 1) * 16384;
    const u16* src = (part >> 1) ? Bt : A;
    const int g0 = ((part >> 1) ? gn0 : gm0) + (part & 1) * 128;
    const int k0 = kt * 64;
    #pragma unroll
    for (int q = 0; q < 2; ++q) {
      int r = q * 64 + (tid >> 3);
      GLL16(src + (size_t)(g0 + r) * 1024 + k0 + scg * 8,
            smem + sb + q * 8192 + w * 1024);
    }
  };

  f32x4 acc[8][4] = {};

  // prologue: tiles 0 and 1 fully staged, hard drain
  #pragma unroll
  for (int n = 0; n < 8; ++n) STAGE_HALF(n >> 2, n & 3);
  __syncthreads();

  for (int kt = 0; kt < 16; ++kt) {
    const char* Ab = smem + (kt & 1) * 65536;
    const char* Bb = Ab + 32768;
    const int arow = wr * 128 + l16;            // (row&7)==rsw for all frags
    const int brow = wc * 64 + l16;
    s16x8 aA[4][2], bB[4][2];

    // ---- phase 0: read A rg0 (8) + B cg0 (4); stage A0(kt+1); MFMA rg0.cg0 --
    #pragma unroll
    for (int fi = 0; fi < 4; ++fi) {
      const char* p = Ab + (arow + fi * 16) * 128;
      aA[fi][0] = *(const s16x8*)(p + ((quad ^ rsw) * 16));
      aA[fi][1] = *(const s16x8*)(p + (((4 + quad) ^ rsw) * 16));
    }
    #pragma unroll
    for (int fj = 0; fj < 2; ++fj) {
      const char* p = Bb + (brow + fj * 16) * 128;
      bB[fj][0] = *(const s16x8*)(p + ((quad ^ rsw) * 16));
      bB[fj][1] = *(const s16x8*)(p + (((4 + quad) ^ rsw) * 16));
    }
    if (kt >= 1 && kt < 15) STAGE_HALF(kt + 1, 0);
    __builtin_amdgcn_s_barrier();
    asm volatile("s_waitcnt lgkmcnt(0)" ::: "memory");
    __builtin_amdgcn_sched_barrier(0);
    __builtin_amdgcn_s_setprio(1);
    #pragma unroll
    for (int fi = 0; fi < 4; ++fi)
      #pragma unroll
      for (int fj = 0; fj < 2; ++fj) {
        acc[fi][fj] = MFMA16(aA[fi][0], bB[fj][0], acc[fi][fj]);
        acc[fi][fj] = MFMA16(aA[fi][1], bB[fj][1], acc[fi][fj]);
      }
    __builtin_amdgcn_s_setprio(0);
    __builtin_amdgcn_s_barrier();
    asm volatile("" ::: "memory");

    // ---- phase 1: read B cg1 (4); stage A1(kt+1); MFMA rg0.cg1 --------------
    #pragma unroll
    for (int fj = 0; fj < 2; ++fj) {
      const char* p = Bb + (brow + (2 + fj) * 16) * 128;
      bB[2 + fj][0] = *(const s16x8*)(p + ((quad ^ rsw) * 16));
      bB[2 + fj][1] = *(const s16x8*)(p + (((4 + quad) ^ rsw) * 16));
    }
    if (kt >= 1 && kt < 15) STAGE_HALF(kt + 1, 1);
    __builtin_amdgcn_s_barrier();
    asm volatile("s_waitcnt lgkmcnt(0)" ::: "memory");
    __builtin_amdgcn_sched_barrier(0);
    __builtin_amdgcn_s_setprio(1);
    #pragma unroll
    for (int fi = 0; fi < 4; ++fi)
      #pragma unroll
      for (int fj = 0; fj < 2; ++fj) {
        acc[fi][2 + fj] = MFMA16(aA[fi][0], bB[2 + fj][0], acc[fi][2 + fj]);
        acc[fi][2 + fj] = MFMA16(aA[fi][1], bB[2 + fj][1], acc[fi][2 + fj]);
      }
    __builtin_amdgcn_s_setprio(0);
    __builtin_amdgcn_s_barrier();
    asm volatile("" ::: "memory");

    // ---- phase 2: read A rg1 (8, reuse regs); stage B0(kt+2); MFMA rg1.cg0 --
    #pragma unroll
    for (int fi = 0; fi < 4; ++fi) {
      const char* p = Ab + (arow + (4 + fi) * 16) * 128;
      aA[fi][0] = *(const s16x8*)(p + ((quad ^ rsw) * 16));
      aA[fi][1] = *(const s16x8*)(p + (((4 + quad) ^ rsw) * 16));
    }
    if (kt < 14) STAGE_HALF(kt + 2, 2);
    __builtin_amdgcn_s_barrier();
    asm volatile("s_waitcnt lgkmcnt(0)" ::: "memory");
    __builtin_amdgcn_sched_barrier(0);
    __builtin_amdgcn_s_setprio(1);
    #pragma unroll
    for (int fi = 0; fi < 4; ++fi)
      #pragma unroll
      for (int fj = 0; fj < 2; ++fj) {
        acc[4 + fi][fj] = MFMA16(aA[fi][0], bB[fj][0], acc[4 + fi][fj]);
        acc[4 + fi][fj] = MFMA16(aA[fi][1], bB[fj][1], acc[4 + fi][fj]);
      }
    __builtin_amdgcn_s_setprio(0);
    __builtin_amdgcn_s_barrier();
    asm volatile("" ::: "memory");

    // ---- phase 3: stage B1(kt+2); MFMA rg1.cg1; boundary vmcnt --------------
    if (kt < 14) STAGE_HALF(kt + 2, 3);
    __builtin_amdgcn_s_barrier();
    __builtin_amdgcn_s_setprio(1);
    #pragma unroll
    for (int fi = 0; fi < 4; ++fi)
      #pragma unroll
      for (int fj = 0; fj < 2; ++fj) {
        acc[4 + fi][2 + fj] = MFMA16(aA[fi][0], bB[2 + fj][0], acc[4 + fi][2 + fj]);
        acc[4 + fi][2 + fj] = MFMA16(aA[fi][1], bB[2 + fj][1], acc[4 + fi][2 + fj]);
      }
    __builtin_amdgcn_s_setprio(0);
    if (kt < 14)      asm volatile("s_waitcnt vmcnt(4)" ::: "memory");
    else if (kt < 15) asm volatile("s_waitcnt vmcnt(0)" ::: "memory");
    __builtin_amdgcn_s_barrier();
    asm volatile("" ::: "memory");
  }

  // epilogue: bf16 C write
  #pragma unroll
  for (int g = 0; g < 8; ++g) {
    const int row0 = gm0 + wr * 128 + g * 16 + quad * 4;
    #pragma unroll
    for (int fj = 0; fj < 4; ++fj) {
      const int col = gn0 + wc * 64 + fj * 16 + l16;
      #pragma unroll
      for (int r = 0; r < 4; ++r)
        Cb[(size_t)(row0 + r) * 3072 + col] = f2bf(acc[g][fj][r]);
    }
  }
}

// ---------------- RoPE + reorder ----------------
// qkv (4096 x 3072) bf16 -> Qr,Kr (bh,T,64), Vt (bh,64,T)
// Q pre-scaled by 0.125*log2(e) so attention uses exp2 directly.
__global__ __launch_bounds__(256) void rope_kernel(const u16* __restrict__ qkv,
                                                   u16* __restrict__ Qr,
                                                   u16* __restrict__ Kr,
                                                   u16* __restrict__ Vt) {
  const int tt = blockIdx.x, bh = blockIdx.y;
  const int b = bh >> 4, h = bh & 15;
  const int tid = threadIdx.x;
  const float QSCALE = 0.125f * 1.4426950408889634f;

  #pragma unroll
  for (int ii = 0; ii < 8; ++ii) {
    int idx = ii * 256 + tid;      // 64 tokens x 32 pairs
    int tl = idx >> 5, jj = idx & 31;
    int t = tt * 64 + tl;
    size_t mrow = (size_t)(b * 2048 + t) * 3072 + h * 64;
    float q1 = bf2f(qkv[mrow + jj]),        q2 = bf2f(qkv[mrow + 32 + jj]);
    float k1 = bf2f(qkv[mrow + 1024 + jj]), k2 = bf2f(qkv[mrow + 1024 + 32 + jj]);
    float invf = exp2f(-(float)jj * (13.287712379549449f / 32.0f));  // 10000^(-j/32)
    float ang = (float)t * invf;
    float sn, cs;
    sincosf(ang, &sn, &cs);
    size_t orow = (size_t)(bh * 2048 + t) * 64;
    Qr[orow + jj]      = f2bf((q1 * cs - q2 * sn) * QSCALE);
    Qr[orow + 32 + jj] = f2bf((q2 * cs + q1 * sn) * QSCALE);
    Kr[orow + jj]      = f2bf(k1 * cs - k2 * sn);
    Kr[orow + 32 + jj] = f2bf(k2 * cs + k1 * sn);
  }

  // V transpose 64x64 via LDS
  __shared__ __attribute__((aligned(16))) u16 Vl[64][72];
  for (int s = tid; s < 512; s += 256) {
    int r = s >> 3, c8 = (s & 7) * 8;
    *(uint4*)&Vl[r][c8] =
        *(const uint4*)&qkv[(size_t)(b * 2048 + tt * 64 + r) * 3072 + 2048 + h * 64 + c8];
  }
  __syncthreads();
  for (int s = tid; s < 512; s += 256) {
    int d = s >> 3, t8 = (s & 7) * 8;
    u16 tmp[8];
    #pragma unroll
    for (int k = 0; k < 8; ++k) tmp[k] = Vl[t8 + k][d];
    *(uint4*)&Vt[(size_t)(bh * 64 + d) * 2048 + tt * 64 + t8] = *(uint4*)tmp;
  }
}

// ---------------- Flash attention v8c (unchanged, passing @ ~39 us) ----------
__global__ __launch_bounds__(512) void attn_kernel(const u16* __restrict__ Qr,
                                                   const u16* __restrict__ Kr,
                                                   const u16* __restrict__ Vt,
                                                   u16* __restrict__ AO) {
  // [0,32K): K[par*2+d][8192]  [32K,64K): V[par*2+d][8192]  [64K,100K): P[8][4608]
  __shared__ __attribute__((aligned(16))) char smem[102400];
  const int tid = threadIdx.x;
  const int w = tid >> 6, lane = tid & 63;
  const int wq = w & 3, wp = w >> 2;          // compute roles: q-quarter, j-parity
  const int quad = lane >> 4, l16 = lane & 15;
  const int id = blockIdx.x;
  const int bh = id & 31;                     // id%8 = bh%8 -> per-bh XCD affinity
  const int c  = id >> 5;                     // pair index 0..7
  const int b = bh >> 4, h = bh & 15;
  const size_t qkb = (size_t)bh * (2048 * 64);
  const size_t vtb = (size_t)bh * (64 * 2048);
  u16* Pw = (u16*)(smem + 65536 + w * 4608);

  const int srow = lane >> 3;                 // row within an 8-row issue
  const int scg  = (lane & 7) ^ srow;         // pre-swizzled 16B col group
  const int smat = w & 1, stp = (w >> 1) & 1, shalf = (w >> 2) & 1;

  auto STAGE = [&](int j0, int d) {
    const int jn = j0 + stp;
    if (smat == 0) {
      #pragma unroll
      for (int ii = 0; ii < 4; ++ii) {
        int i = shalf * 4 + ii;               // 8-row block 0..7
        GLL16(Kr + qkb + (size_t)(jn * 64 + i * 8 + srow) * 64 + scg * 8,
              smem + (stp * 2 + d) * 8192 + i * 1024);
      }
    } else {
      #pragma unroll
      for (int ii = 0; ii < 4; ++ii) {
        int i = shalf * 4 + ii;               // 8 d-rows each
        GLL16(Vt + vtb + (size_t)(i * 8 + srow) * 2048 + jn * 64 + scg * 8,
              smem + 32768 + (stp * 2 + d) * 8192 + i * 1024);
      }
    }
  };

  for (int t = 0; t < 2; ++t) {
    const int qblk = t ? (15 - c) : c;
    const int q0w = qblk * 128 + wq * 32;     // this wave's 32 q-rows
    const int steps = qblk + 1;               // j-tiles = 2*steps (always even)

    s16x8 bQ[2][2];
    #pragma unroll
    for (int s = 0; s < 2; ++s)
      #pragma unroll
      for (int hf = 0; hf < 2; ++hf)
        bQ[s][hf] = *(const s16x8*)&Qr[qkb + (size_t)(q0w + s * 16 + l16) * 64 + hf * 32 + quad * 8];

    f32x4 O[2][4] = {};
    float l_run[2] = {0.0f, 0.0f};

    STAGE(0, 0);
    __syncthreads();

    for (int st = 0; st < steps; ++st) {
      const int cur = st & 1;
      if (st + 1 < steps) STAGE(2 * st + 2, cur ^ 1);

      const int j = 2 * st + wp;
      if (j * 64 <= q0w + 31) {
        const u16* Kb = (const u16*)(smem + (wp * 2 + cur) * 8192);
        const u16* Vb = (const u16*)(smem + 32768 + (wp * 2 + cur) * 8192);
        const bool masked = (j * 64 + 63 > q0w);
        const int rsw = (l16 & 7);

        s16x8 aK[4][2];
        #pragma unroll
        for (int kt = 0; kt < 4; ++kt)
          #pragma unroll
          for (int hf = 0; hf < 2; ++hf)
            aK[kt][hf] = *(const s16x8*)&Kb[(kt * 16 + l16) * 64 + (((hf * 4 + quad) ^ rsw) * 8)];

        f32x4 S[2][4];
        __builtin_amdgcn_s_setprio(1);
        #pragma unroll
        for (int kt = 0; kt < 4; ++kt)
          #pragma unroll
          for (int s = 0; s < 2; ++s) {
            f32x4 z = {};
            z = MFMA16(aK[kt][0], bQ[s][0], z);
            S[s][kt] = MFMA16(aK[kt][1], bQ[s][1], z);
          }
        __builtin_amdgcn_s_setprio(0);

        if (masked) {
          #pragma unroll
          for (int s = 0; s < 2; ++s) {
            int q = q0w + s * 16 + l16;
            #pragma unroll
            for (int kt = 0; kt < 4; ++kt) {
              int key0 = j * 64 + kt * 16 + quad * 4;
              #pragma unroll
              for (int r = 0; r < 4; ++r)
                if (key0 + r > q) S[s][kt][r] = -1e30f;
            }
          }
        }

        #pragma unroll
        for (int s = 0; s < 2; ++s) {
          float sum = 0.0f;
          #pragma unroll
          for (int kt = 0; kt < 4; ++kt) {
            #pragma unroll
            for (int r = 0; r < 4; ++r) {
              float e = fexp2(S[s][kt][r]);
              S[s][kt][r] = e;
              sum += e;
            }
          }
          sum += __shfl_xor(sum, 16);
          sum += __shfl_xor(sum, 32);
          l_run[s] += sum;
          #pragma unroll
          for (int kt = 0; kt < 4; ++kt) {
            uint2 pw;
            pw.x = pk2bf(S[s][kt][0], S[s][kt][1]);
            pw.y = pk2bf(S[s][kt][2], S[s][kt][3]);
            *(uint2*)&Pw[s * 1152 + l16 * 72 + kt * 16 + quad * 4] = pw;
          }
        }

        s16x8 bP[2][2];
        #pragma unroll
        for (int s = 0; s < 2; ++s) {
          bP[s][0] = *(const s16x8*)&Pw[s * 1152 + l16 * 72 + quad * 8];
          bP[s][1] = *(const s16x8*)&Pw[s * 1152 + l16 * 72 + 32 + quad * 8];
        }
        s16x8 aV[4][2];
        #pragma unroll
        for (int dt = 0; dt < 4; ++dt)
          #pragma unroll
          for (int hf = 0; hf < 2; ++hf)
            aV[dt][hf] = *(const s16x8*)&Vb[(dt * 16 + l16) * 64 + (((hf * 4 + quad) ^ rsw) * 8)];

        __builtin_amdgcn_s_setprio(1);
        #pragma unroll
        for (int dt = 0; dt < 4; ++dt)
          #pragma unroll
          for (int s = 0; s < 2; ++s) {
            O[s][dt] = MFMA16(aV[dt][0], bP[s][0], O[s][dt]);
            O[s][dt] = MFMA16(aV[dt][1], bP[s][1], O[s][dt]);
          }
        __builtin_amdgcn_s_setprio(0);
      }

      __syncthreads();
    }

    // ---- parity combine (exact) ----
    if (wp == 1) {
      float* Lsl = (float*)(smem + 65536 + wq * 512);
      Lsl[lane]      = l_run[0];
      Lsl[64 + lane] = l_run[1];
      f32x4* slot = (f32x4*)smem + wq * 512;
      #pragma unroll
      for (int s = 0; s < 2; ++s)
        #pragma unroll
        for (int dt = 0; dt < 4; ++dt)
          slot[(s * 4 + dt) * 64 + lane] = O[s][dt];
    }
    __syncthreads();
    if (wp == 0) {
      const float* Lsl = (const float*)(smem + 65536 + wq * 512);
      const f32x4* slot = (const f32x4*)smem + wq * 512;
      #pragma unroll
      for (int s = 0; s < 2; ++s) {
        float l_tot = l_run[s] + Lsl[s * 64 + lane];
        float inv = __builtin_amdgcn_rcpf(l_tot);
        int q = q0w + s * 16 + l16;
        #pragma unroll
        for (int dt = 0; dt < 4; ++dt) {
          f32x4 o = O[s][dt] + slot[(s * 4 + dt) * 64 + lane];
          uint2 ow;
          ow.x = pk2bf(o[0] * inv, o[1] * inv);
          ow.y = pk2bf(o[2] * inv, o[3] * inv);
          *(uint2*)&AO[(size_t)(b * 2048 + q) * 1024 + h * 64 + dt * 16 + quad * 4] = ow;
        }
      }
    }
    __syncthreads();
  }
}

// ---------------- launcher ----------------
extern "C" void kernel_launch(void* const* d_in, const int* in_sizes, int n_in,
                              void* d_out, int out_size, void* d_ws, size_t ws_size,
                              hipStream_t stream) {
  const float* x      = (const float*)d_in[0];
  const float* norm_w = (const float*)d_in[1];
  const float* w_qkv  = (const float*)d_in[2];
  const float* w_out  = (const float*)d_in[3];
  float* out = (float*)d_out;

  u16* ws     = (u16*)d_ws;
  u16* wqkv_b = ws;                      // 3 145 728
  u16* wout_b = wqkv_b + 3145728;        // 1 048 576
  u16* h_b    = wout_b + 1048576;        // 4 194 304
  u16* qkv_b  = h_b + 4194304;           // 12 582 912
  u16* Qr     = qkv_b + 12582912;        // 4 194 304
  u16* Kr     = Qr + 4194304;            // 4 194 304
  u16* Vt     = Kr + 4194304;            // 4 194 304
  u16* AO     = Vt + 4194304;            // 4 194 304  (total ~75.5 MB)

  prep_kernel<<<8192, 256, 0, stream>>>(x, norm_w, w_qkv, w_out, h_b, wqkv_b, wout_b);
  gemm256<<<192, 512, 0, stream>>>(h_b, wqkv_b, qkv_b);
  rope_kernel<<<dim3(32, 32), 256, 0, stream>>>(qkv_b, Qr, Kr, Vt);
  attn_kernel<<<256, 512, 0, stream>>>(Qr, Kr, Vt, AO);
  gemm_bt<1><<<dim3(8, 32), 256, 0, stream>>>(AO, wout_b, nullptr, out, x,
                                              4096, 1024, 1024);
}

// Round 7
// 185.413 us; speedup vs baseline: 1.2163x; 1.0034x over previous
//
#include <hip/hip_runtime.h>
#include <math.h>

typedef unsigned short u16;
typedef unsigned int u32;
typedef __attribute__((ext_vector_type(4))) float f32x4;
typedef __attribute__((ext_vector_type(8))) short s16x8;

#define GLL16(g, l) __builtin_amdgcn_global_load_lds( \
    (const __attribute__((address_space(1))) void*)(g), \
    (__attribute__((address_space(3))) void*)(l), 16, 0, 0)

#define MFMA16(a, b, c) __builtin_amdgcn_mfma_f32_16x16x32_bf16(a, b, c, 0, 0, 0)

__device__ __forceinline__ u16 f2bf(float f) {
  union { float f; u32 u; } v; v.f = f;
  u32 r = v.u + 0x7FFFu + ((v.u >> 16) & 1u);
  return (u16)(r >> 16);
}
__device__ __forceinline__ float bf2f(u16 h) {
  union { u32 u; float f; } v; v.u = ((u32)h) << 16;
  return v.f;
}
// pack two floats to bf16x2 (round-half-up) in one v_perm
__device__ __forceinline__ u32 pk2bf(float lo, float hi) {
  union { float f; u32 u; } a, b; a.f = lo; b.f = hi;
  return __builtin_amdgcn_perm(b.u + 0x8000u, a.u + 0x8000u, 0x07060302u);
}
__device__ __forceinline__ float fexp2(float x) {
#if __has_builtin(__builtin_amdgcn_exp2f)
  return __builtin_amdgcn_exp2f(x);
#else
  return exp2f(x);
#endif
}

// ---------------- fused prep: rmsnorm + both weight casts (1 launch) ----------
__global__ __launch_bounds__(256) void prep_kernel(const float* __restrict__ x,
                                                   const float* __restrict__ wgt,
                                                   const float* __restrict__ w_qkv,
                                                   const float* __restrict__ w_out,
                                                   u16* __restrict__ h,
                                                   u16* __restrict__ wqkv_b,
                                                   u16* __restrict__ wout_b) {
  __shared__ float red[4];
  const int bid = blockIdx.x, tid = threadIdx.x;
  if (bid < 4096) {
    // RMSNorm row
    const int row = bid;
    const float4 v = *(const float4*)&x[(size_t)row * 1024 + tid * 4];
    float ss = v.x * v.x + v.y * v.y + v.z * v.z + v.w * v.w;
    ss += __shfl_xor(ss, 1);  ss += __shfl_xor(ss, 2);  ss += __shfl_xor(ss, 4);
    ss += __shfl_xor(ss, 8);  ss += __shfl_xor(ss, 16); ss += __shfl_xor(ss, 32);
    if ((tid & 63) == 0) red[tid >> 6] = ss;
    __syncthreads();
    const float tot = red[0] + red[1] + red[2] + red[3];
    const float s = rsqrtf(tot * (1.0f / 1024.0f) + 1e-6f);
    const float4 g = *(const float4*)&wgt[tid * 4];
    uint2 o;
    o.x = (u32)f2bf(v.x * s * g.x) | ((u32)f2bf(v.y * s * g.y) << 16);
    o.y = (u32)f2bf(v.z * s * g.z) | ((u32)f2bf(v.w * s * g.w) << 16);
    *(uint2*)&h[(size_t)row * 1024 + tid * 4] = o;
  } else if (bid < 7168) {
    int i = (bid - 4096) * 256 + tid;          // 786432 float4 of w_qkv
    float4 v = ((const float4*)w_qkv)[i];
    uint2 o;
    o.x = (u32)f2bf(v.x) | ((u32)f2bf(v.y) << 16);
    o.y = (u32)f2bf(v.z) | ((u32)f2bf(v.w) << 16);
    ((uint2*)wqkv_b)[i] = o;
  } else {
    int i = (bid - 7168) * 256 + tid;          // 262144 float4 of w_out
    float4 v = ((const float4*)w_out)[i];
    uint2 o;
    o.x = (u32)f2bf(v.x) | ((u32)f2bf(v.y) << 16);
    o.y = (u32)f2bf(v.z) | ((u32)f2bf(v.w) << 16);
    ((uint2*)wout_b)[i] = o;
  }
}

// ---------------- GEMM 128^2 (kept for out-proj): C = A * Bt^T ----------------
template <int EPI>  // 0: write bf16 C. 1: write fp32 C = acc + resid
__global__ __launch_bounds__(256) void gemm_bt(const u16* __restrict__ A,
                                               const u16* __restrict__ Bt,
                                               u16* __restrict__ Cb,
                                               float* __restrict__ Cf,
                                               const float* __restrict__ resid,
                                               int M, int N, int K) {
  __shared__ __attribute__((aligned(16))) u16 As[128 * 32];
  __shared__ __attribute__((aligned(16))) u16 Bs[128 * 32];
  const int tid = threadIdx.x;
  const int w = tid >> 6, lane = tid & 63;
  const int quad = lane >> 4, l16 = lane & 15;
  const int gm0 = blockIdx.y * 128, gn0 = blockIdx.x * 128;
  const int wm = (w & 1) * 64, wn = (w >> 1) * 64;

  f32x4 acc[4][4] = {};

  for (int k0 = 0; k0 < K; k0 += 32) {
    __syncthreads();
    if (w < 2) {
      #pragma unroll
      for (int i = 0; i < 4; ++i) {
        int sb = (w * 4 + i) * 64;
        int slot = sb + lane;
        int m = slot >> 2, c = (slot & 3) ^ (m & 3);
        GLL16(A + (size_t)(gm0 + m) * K + k0 + c * 8, &As[sb * 8]);
      }
    } else {
      #pragma unroll
      for (int i = 0; i < 4; ++i) {
        int sb = ((w - 2) * 4 + i) * 64;
        int slot = sb + lane;
        int n = slot >> 2, c = (slot & 3) ^ (n & 3);
        GLL16(Bt + (size_t)(gn0 + n) * K + k0 + c * 8, &Bs[sb * 8]);
      }
    }
    __syncthreads();
    s16x8 aF[4], bF[4];
    #pragma unroll
    for (int i = 0; i < 4; ++i) {
      int m = wm + i * 16 + l16;
      aF[i] = *(const s16x8*)&As[(m * 4 + (quad ^ (m & 3))) * 8];
    }
    #pragma unroll
    for (int j = 0; j < 4; ++j) {
      int n = wn + j * 16 + l16;
      bF[j] = *(const s16x8*)&Bs[(n * 4 + (quad ^ (n & 3))) * 8];
    }
    #pragma unroll
    for (int i = 0; i < 4; ++i)
      #pragma unroll
      for (int j = 0; j < 4; ++j)
        acc[i][j] = MFMA16(aF[i], bF[j], acc[i][j]);
  }

  #pragma unroll
  for (int i = 0; i < 4; ++i) {
    int row0 = gm0 + wm + i * 16 + quad * 4;
    #pragma unroll
    for (int j = 0; j < 4; ++j) {
      int col = gn0 + wn + j * 16 + l16;
      #pragma unroll
      for (int r = 0; r < 4; ++r) {
        size_t idx = (size_t)(row0 + r) * N + col;
        if (EPI == 0) Cb[idx] = f2bf(acc[i][j][r]);
        else          Cf[idx] = acc[i][j][r] + resid[idx];
      }
    }
  }
}

// ---------------- GEMM 256^2 8-phase (QKV matmul, M=4096 N=3072 K=1024) -------
// R6 post-mortem: without a min-waves clause the compiler may allocate >256
// VGPR/wave (gfx950 allows 512) -> 1 wave/SIMD -> every barrier/LDS latency
// exposed (measured ~41 us = 1530 cyc/phase vs ~400 issue content).
// __launch_bounds__(512, 2) pins 2 waves/SIMD (VGPR <= 256; live state ~220).
__global__ __launch_bounds__(512, 2) void gemm256(const u16* __restrict__ A,
                                                  const u16* __restrict__ Bt,
                                                  u16* __restrict__ Cb) {
  __shared__ __attribute__((aligned(16))) char smem[131072];
  const int tid = threadIdx.x;
  const int w = tid >> 6, lane = tid & 63;
  const int quad = lane >> 4, l16 = lane & 15;
  const int wr = w >> 2, wc = w & 3;
  const int rsw = l16 & 7;
  const int id = blockIdx.x;
  const int sw = (id & 7) * 24 + (id >> 3);    // XCD swizzle, 192 = 8 x 24
  const int by = sw / 12, bx = sw - by * 12;
  const int gm0 = by * 256, gn0 = bx * 256;
  const int scg = (lane & 7) ^ (lane >> 3);    // pre-swizzled src col-group

  // part: 0=A half0, 1=A half1, 2=B half0, 3=B half1 (half = 128 rows)
  auto STAGE_HALF = [&](int kt, int part) {
    const int sb = (kt & 1) * 65536 + (part >> 1) * 32768 + (part & 1) * 16384;
    const u16* src = (part >> 1) ? Bt : A;
    const int g0 = ((part >> 1) ? gn0 : gm0) + (part & 1) * 128;
    const int k0 = kt * 64;
    #pragma unroll
    for (int q = 0; q < 2; ++q) {
      int r = q * 64 + (tid >> 3);
      GLL16(src + (size_t)(g0 + r) * 1024 + k0 + scg * 8,
            smem + sb + q * 8192 + w * 1024);
    }
  };

  f32x4 acc[8][4] = {};

  // prologue: tiles 0 and 1 fully staged, hard drain
  #pragma unroll
  for (int n = 0; n < 8; ++n) STAGE_HALF(n >> 2, n & 3);
  __syncthreads();

  for (int kt = 0; kt < 16; ++kt) {
    const char* Ab = smem + (kt & 1) * 65536;
    const char* Bb = Ab + 32768;
    const int arow = wr * 128 + l16;            // (row&7)==rsw for all frags
    const int brow = wc * 64 + l16;
    s16x8 aA[4][2], bB[4][2];

    // ---- phase 0: read A rg0 (8) + B cg0 (4); stage A0(kt+1); MFMA rg0.cg0 --
    #pragma unroll
    for (int fi = 0; fi < 4; ++fi) {
      const char* p = Ab + (arow + fi * 16) * 128;
      aA[fi][0] = *(const s16x8*)(p + ((quad ^ rsw) * 16));
      aA[fi][1] = *(const s16x8*)(p + (((4 + quad) ^ rsw) * 16));
    }
    #pragma unroll
    for (int fj = 0; fj < 2; ++fj) {
      const char* p = Bb + (brow + fj * 16) * 128;
      bB[fj][0] = *(const s16x8*)(p + ((quad ^ rsw) * 16));
      bB[fj][1] = *(const s16x8*)(p + (((4 + quad) ^ rsw) * 16));
    }
    if (kt >= 1 && kt < 15) STAGE_HALF(kt + 1, 0);
    __builtin_amdgcn_s_barrier();
    asm volatile("s_waitcnt lgkmcnt(0)" ::: "memory");
    __builtin_amdgcn_sched_barrier(0);
    __builtin_amdgcn_s_setprio(1);
    #pragma unroll
    for (int fi = 0; fi < 4; ++fi)
      #pragma unroll
      for (int fj = 0; fj < 2; ++fj) {
        acc[fi][fj] = MFMA16(aA[fi][0], bB[fj][0], acc[fi][fj]);
        acc[fi][fj] = MFMA16(aA[fi][1], bB[fj][1], acc[fi][fj]);
      }
    __builtin_amdgcn_s_setprio(0);
    __builtin_amdgcn_s_barrier();
    asm volatile("" ::: "memory");

    // ---- phase 1: read B cg1 (4); stage A1(kt+1); MFMA rg0.cg1 --------------
    #pragma unroll
    for (int fj = 0; fj < 2; ++fj) {
      const char* p = Bb + (brow + (2 + fj) * 16) * 128;
      bB[2 + fj][0] = *(const s16x8*)(p + ((quad ^ rsw) * 16));
      bB[2 + fj][1] = *(const s16x8*)(p + (((4 + quad) ^ rsw) * 16));
    }
    if (kt >= 1 && kt < 15) STAGE_HALF(kt + 1, 1);
    __builtin_amdgcn_s_barrier();
    asm volatile("s_waitcnt lgkmcnt(0)" ::: "memory");
    __builtin_amdgcn_sched_barrier(0);
    __builtin_amdgcn_s_setprio(1);
    #pragma unroll
    for (int fi = 0; fi < 4; ++fi)
      #pragma unroll
      for (int fj = 0; fj < 2; ++fj) {
        acc[fi][2 + fj] = MFMA16(aA[fi][0], bB[2 + fj][0], acc[fi][2 + fj]);
        acc[fi][2 + fj] = MFMA16(aA[fi][1], bB[2 + fj][1], acc[fi][2 + fj]);
      }
    __builtin_amdgcn_s_setprio(0);
    __builtin_amdgcn_s_barrier();
    asm volatile("" ::: "memory");

    // ---- phase 2: read A rg1 (8, reuse regs); stage B0(kt+2); MFMA rg1.cg0 --
    #pragma unroll
    for (int fi = 0; fi < 4; ++fi) {
      const char* p = Ab + (arow + (4 + fi) * 16) * 128;
      aA[fi][0] = *(const s16x8*)(p + ((quad ^ rsw) * 16));
      aA[fi][1] = *(const s16x8*)(p + (((4 + quad) ^ rsw) * 16));
    }
    if (kt < 14) STAGE_HALF(kt + 2, 2);
    __builtin_amdgcn_s_barrier();
    asm volatile("s_waitcnt lgkmcnt(0)" ::: "memory");
    __builtin_amdgcn_sched_barrier(0);
    __builtin_amdgcn_s_setprio(1);
    #pragma unroll
    for (int fi = 0; fi < 4; ++fi)
      #pragma unroll
      for (int fj = 0; fj < 2; ++fj) {
        acc[4 + fi][fj] = MFMA16(aA[fi][0], bB[fj][0], acc[4 + fi][fj]);
        acc[4 + fi][fj] = MFMA16(aA[fi][1], bB[fj][1], acc[4 + fi][fj]);
      }
    __builtin_amdgcn_s_setprio(0);
    __builtin_amdgcn_s_barrier();
    asm volatile("" ::: "memory");

    // ---- phase 3: stage B1(kt+2); MFMA rg1.cg1; boundary vmcnt --------------
    if (kt < 14) STAGE_HALF(kt + 2, 3);
    __builtin_amdgcn_s_barrier();
    __builtin_amdgcn_s_setprio(1);
    #pragma unroll
    for (int fi = 0; fi < 4; ++fi)
      #pragma unroll
      for (int fj = 0; fj < 2; ++fj) {
        acc[4 + fi][2 + fj] = MFMA16(aA[fi][0], bB[2 + fj][0], acc[4 + fi][2 + fj]);
        acc[4 + fi][2 + fj] = MFMA16(aA[fi][1], bB[2 + fj][1], acc[4 + fi][2 + fj]);
      }
    __builtin_amdgcn_s_setprio(0);
    if (kt < 14)      asm volatile("s_waitcnt vmcnt(4)" ::: "memory");
    else if (kt < 15) asm volatile("s_waitcnt vmcnt(0)" ::: "memory");
    __builtin_amdgcn_s_barrier();
    asm volatile("" ::: "memory");
  }

  // epilogue: bf16 C write
  #pragma unroll
  for (int g = 0; g < 8; ++g) {
    const int row0 = gm0 + wr * 128 + g * 16 + quad * 4;
    #pragma unroll
    for (int fj = 0; fj < 4; ++fj) {
      const int col = gn0 + wc * 64 + fj * 16 + l16;
      #pragma unroll
      for (int r = 0; r < 4; ++r)
        Cb[(size_t)(row0 + r) * 3072 + col] = f2bf(acc[g][fj][r]);
    }
  }
}

// ---------------- RoPE + reorder ----------------
// qkv (4096 x 3072) bf16 -> Qr,Kr (bh,T,64), Vt (bh,64,T)
// Q pre-scaled by 0.125*log2(e) so attention uses exp2 directly.
__global__ __launch_bounds__(256) void rope_kernel(const u16* __restrict__ qkv,
                                                   u16* __restrict__ Qr,
                                                   u16* __restrict__ Kr,
                                                   u16* __restrict__ Vt) {
  const int tt = blockIdx.x, bh = blockIdx.y;
  const int b = bh >> 4, h = bh & 15;
  const int tid = threadIdx.x;
  const float QSCALE = 0.125f * 1.4426950408889634f;

  #pragma unroll
  for (int ii = 0; ii < 8; ++ii) {
    int idx = ii * 256 + tid;      // 64 tokens x 32 pairs
    int tl = idx >> 5, jj = idx & 31;
    int t = tt * 64 + tl;
    size_t mrow = (size_t)(b * 2048 + t) * 3072 + h * 64;
    float q1 = bf2f(qkv[mrow + jj]),        q2 = bf2f(qkv[mrow + 32 + jj]);
    float k1 = bf2f(qkv[mrow + 1024 + jj]), k2 = bf2f(qkv[mrow + 1024 + 32 + jj]);
    float invf = exp2f(-(float)jj * (13.287712379549449f / 32.0f));  // 10000^(-j/32)
    float ang = (float)t * invf;
    float sn, cs;
    sincosf(ang, &sn, &cs);
    size_t orow = (size_t)(bh * 2048 + t) * 64;
    Qr[orow + jj]      = f2bf((q1 * cs - q2 * sn) * QSCALE);
    Qr[orow + 32 + jj] = f2bf((q2 * cs + q1 * sn) * QSCALE);
    Kr[orow + jj]      = f2bf(k1 * cs - k2 * sn);
    Kr[orow + 32 + jj] = f2bf(k2 * cs + k1 * sn);
  }

  // V transpose 64x64 via LDS
  __shared__ __attribute__((aligned(16))) u16 Vl[64][72];
  for (int s = tid; s < 512; s += 256) {
    int r = s >> 3, c8 = (s & 7) * 8;
    *(uint4*)&Vl[r][c8] =
        *(const uint4*)&qkv[(size_t)(b * 2048 + tt * 64 + r) * 3072 + 2048 + h * 64 + c8];
  }
  __syncthreads();
  for (int s = tid; s < 512; s += 256) {
    int d = s >> 3, t8 = (s & 7) * 8;
    u16 tmp[8];
    #pragma unroll
    for (int k = 0; k < 8; ++k) tmp[k] = Vl[t8 + k][d];
    *(uint4*)&Vt[(size_t)(bh * 64 + d) * 2048 + tt * 64 + t8] = *(uint4*)tmp;
  }
}

// ---------------- Flash attention v8c + occupancy pin ------------------------
// R6: __launch_bounds__(512, 2) pins 2 waves/SIMD (parity-pair latency hiding
// requires both parity waves resident per SIMD; live state ~160 VGPR).
__global__ __launch_bounds__(512, 2) void attn_kernel(const u16* __restrict__ Qr,
                                                      const u16* __restrict__ Kr,
                                                      const u16* __restrict__ Vt,
                                                      u16* __restrict__ AO) {
  // [0,32K): K[par*2+d][8192]  [32K,64K): V[par*2+d][8192]  [64K,100K): P[8][4608]
  __shared__ __attribute__((aligned(16))) char smem[102400];
  const int tid = threadIdx.x;
  const int w = tid >> 6, lane = tid & 63;
  const int wq = w & 3, wp = w >> 2;          // compute roles: q-quarter, j-parity
  const int quad = lane >> 4, l16 = lane & 15;
  const int id = blockIdx.x;
  const int bh = id & 31;                     // id%8 = bh%8 -> per-bh XCD affinity
  const int c  = id >> 5;                     // pair index 0..7
  const int b = bh >> 4, h = bh & 15;
  const size_t qkb = (size_t)bh * (2048 * 64);
  const size_t vtb = (size_t)bh * (64 * 2048);
  u16* Pw = (u16*)(smem + 65536 + w * 4608);

  const int srow = lane >> 3;                 // row within an 8-row issue
  const int scg  = (lane & 7) ^ srow;         // pre-swizzled 16B col group
  const int smat = w & 1, stp = (w >> 1) & 1, shalf = (w >> 2) & 1;

  auto STAGE = [&](int j0, int d) {
    const int jn = j0 + stp;
    if (smat == 0) {
      #pragma unroll
      for (int ii = 0; ii < 4; ++ii) {
        int i = shalf * 4 + ii;               // 8-row block 0..7
        GLL16(Kr + qkb + (size_t)(jn * 64 + i * 8 + srow) * 64 + scg * 8,
              smem + (stp * 2 + d) * 8192 + i * 1024);
      }
    } else {
      #pragma unroll
      for (int ii = 0; ii < 4; ++ii) {
        int i = shalf * 4 + ii;               // 8 d-rows each
        GLL16(Vt + vtb + (size_t)(i * 8 + srow) * 2048 + jn * 64 + scg * 8,
              smem + 32768 + (stp * 2 + d) * 8192 + i * 1024);
      }
    }
  };

  for (int t = 0; t < 2; ++t) {
    const int qblk = t ? (15 - c) : c;
    const int q0w = qblk * 128 + wq * 32;     // this wave's 32 q-rows
    const int steps = qblk + 1;               // j-tiles = 2*steps (always even)

    s16x8 bQ[2][2];
    #pragma unroll
    for (int s = 0; s < 2; ++s)
      #pragma unroll
      for (int hf = 0; hf < 2; ++hf)
        bQ[s][hf] = *(const s16x8*)&Qr[qkb + (size_t)(q0w + s * 16 + l16) * 64 + hf * 32 + quad * 8];

    f32x4 O[2][4] = {};
    float l_run[2] = {0.0f, 0.0f};

    STAGE(0, 0);
    __syncthreads();

    for (int st = 0; st < steps; ++st) {
      const int cur = st & 1;
      if (st + 1 < steps) STAGE(2 * st + 2, cur ^ 1);

      const int j = 2 * st + wp;
      if (j * 64 <= q0w + 31) {
        const u16* Kb = (const u16*)(smem + (wp * 2 + cur) * 8192);
        const u16* Vb = (const u16*)(smem + 32768 + (wp * 2 + cur) * 8192);
        const bool masked = (j * 64 + 63 > q0w);
        const int rsw = (l16 & 7);

        s16x8 aK[4][2];
        #pragma unroll
        for (int kt = 0; kt < 4; ++kt)
          #pragma unroll
          for (int hf = 0; hf < 2; ++hf)
            aK[kt][hf] = *(const s16x8*)&Kb[(kt * 16 + l16) * 64 + (((hf * 4 + quad) ^ rsw) * 8)];

        f32x4 S[2][4];
        __builtin_amdgcn_s_setprio(1);
        #pragma unroll
        for (int kt = 0; kt < 4; ++kt)
          #pragma unroll
          for (int s = 0; s < 2; ++s) {
            f32x4 z = {};
            z = MFMA16(aK[kt][0], bQ[s][0], z);
            S[s][kt] = MFMA16(aK[kt][1], bQ[s][1], z);
          }
        __builtin_amdgcn_s_setprio(0);

        if (masked) {
          #pragma unroll
          for (int s = 0; s < 2; ++s) {
            int q = q0w + s * 16 + l16;
            #pragma unroll
            for (int kt = 0; kt < 4; ++kt) {
              int key0 = j * 64 + kt * 16 + quad * 4;
              #pragma unroll
              for (int r = 0; r < 4; ++r)
                if (key0 + r > q) S[s][kt][r] = -1e30f;
            }
          }
        }

        #pragma unroll
        for (int s = 0; s < 2; ++s) {
          float sum = 0.0f;
          #pragma unroll
          for (int kt = 0; kt < 4; ++kt) {
            #pragma unroll
            for (int r = 0; r < 4; ++r) {
              float e = fexp2(S[s][kt][r]);
              S[s][kt][r] = e;
              sum += e;
            }
          }
          sum += __shfl_xor(sum, 16);
          sum += __shfl_xor(sum, 32);
          l_run[s] += sum;
          #pragma unroll
          for (int kt = 0; kt < 4; ++kt) {
            uint2 pw;
            pw.x = pk2bf(S[s][kt][0], S[s][kt][1]);
            pw.y = pk2bf(S[s][kt][2], S[s][kt][3]);
            *(uint2*)&Pw[s * 1152 + l16 * 72 + kt * 16 + quad * 4] = pw;
          }
        }

        s16x8 bP[2][2];
        #pragma unroll
        for (int s = 0; s < 2; ++s) {
          bP[s][0] = *(const s16x8*)&Pw[s * 1152 + l16 * 72 + quad * 8];
          bP[s][1] = *(const s16x8*)&Pw[s * 1152 + l16 * 72 + 32 + quad * 8];
        }
        s16x8 aV[4][2];
        #pragma unroll
        for (int dt = 0; dt < 4; ++dt)
          #pragma unroll
          for (int hf = 0; hf < 2; ++hf)
            aV[dt][hf] = *(const s16x8*)&Vb[(dt * 16 + l16) * 64 + (((hf * 4 + quad) ^ rsw) * 8)];

        __builtin_amdgcn_s_setprio(1);
        #pragma unroll
        for (int dt = 0; dt < 4; ++dt)
          #pragma unroll
          for (int s = 0; s < 2; ++s) {
            O[s][dt] = MFMA16(aV[dt][0], bP[s][0], O[s][dt]);
            O[s][dt] = MFMA16(aV[dt][1], bP[s][1], O[s][dt]);
          }
        __builtin_amdgcn_s_setprio(0);
      }

      __syncthreads();
    }

    // ---- parity combine (exact) ----
    if (wp == 1) {
      float* Lsl = (float*)(smem + 65536 + wq * 512);
      Lsl[lane]      = l_run[0];
      Lsl[64 + lane] = l_run[1];
      f32x4* slot = (f32x4*)smem + wq * 512;
      #pragma unroll
      for (int s = 0; s < 2; ++s)
        #pragma unroll
        for (int dt = 0; dt < 4; ++dt)
          slot[(s * 4 + dt) * 64 + lane] = O[s][dt];
    }
    __syncthreads();
    if (wp == 0) {
      const float* Lsl = (const float*)(smem + 65536 + wq * 512);
      const f32x4* slot = (const f32x4*)smem + wq * 512;
      #pragma unroll
      for (int s = 0; s < 2; ++s) {
        float l_tot = l_run[s] + Lsl[s * 64 + lane];
        float inv = __builtin_amdgcn_rcpf(l_tot);
        int q = q0w + s * 16 + l16;
        #pragma unroll
        for (int dt = 0; dt < 4; ++dt) {
          f32x4 o = O[s][dt] + slot[(s * 4 + dt) * 64 + lane];
          uint2 ow;
          ow.x = pk2bf(o[0] * inv, o[1] * inv);
          ow.y = pk2bf(o[2] * inv, o[3] * inv);
          *(uint2*)&AO[(size_t)(b * 2048 + q) * 1024 + h * 64 + dt * 16 + quad * 4] = ow;
        }
      }
    }
    __syncthreads();
  }
}

// ---------------- launcher ----------------
extern "C" void kernel_launch(void* const* d_in, const int* in_sizes, int n_in,
                              void* d_out, int out_size, void* d_ws, size_t ws_size,
                              hipStream_t stream) {
  const float* x      = (const float*)d_in[0];
  const float* norm_w = (const float*)d_in[1];
  const float* w_qkv  = (const float*)d_in[2];
  const float* w_out  = (const float*)d_in[3];
  float* out = (float*)d_out;

  u16* ws     = (u16*)d_ws;
  u16* wqkv_b = ws;                      // 3 145 728
  u16* wout_b = wqkv_b + 3145728;        // 1 048 576
  u16* h_b    = wout_b + 1048576;        // 4 194 304
  u16* qkv_b  = h_b + 4194304;           // 12 582 912
  u16* Qr     = qkv_b + 12582912;        // 4 194 304
  u16* Kr     = Qr + 4194304;            // 4 194 304
  u16* Vt     = Kr + 4194304;            // 4 194 304
  u16* AO     = Vt + 4194304;            // 4 194 304  (total ~75.5 MB)

  prep_kernel<<<8192, 256, 0, stream>>>(x, norm_w, w_qkv, w_out, h_b, wqkv_b, wout_b);
  gemm256<<<192, 512, 0, stream>>>(h_b, wqkv_b, qkv_b);
  rope_kernel<<<dim3(32, 32), 256, 0, stream>>>(qkv_b, Qr, Kr, Vt);
  attn_kernel<<<256, 512, 0, stream>>>(Qr, Kr, Vt, AO);
  gemm_bt<1><<<dim3(8, 32), 256, 0, stream>>>(AO, wout_b, nullptr, out, x,
                                              4096, 1024, 1024);
}

// Round 8
// 183.912 us; speedup vs baseline: 1.2262x; 1.0082x over previous
//
#include <hip/hip_runtime.h>
#include <math.h>

typedef unsigned short u16;
typedef unsigned int u32;
typedef __attribute__((ext_vector_type(4))) float f32x4;
typedef __attribute__((ext_vector_type(8))) short s16x8;

#define GLL16(g, l) __builtin_amdgcn_global_load_lds( \
    (const __attribute__((address_space(1))) void*)(g), \
    (__attribute__((address_space(3))) void*)(l), 16, 0, 0)

#define MFMA16(a, b, c) __builtin_amdgcn_mfma_f32_16x16x32_bf16(a, b, c, 0, 0, 0)

__device__ __forceinline__ u16 f2bf(float f) {
  union { float f; u32 u; } v; v.f = f;
  u32 r = v.u + 0x7FFFu + ((v.u >> 16) & 1u);
  return (u16)(r >> 16);
}
__device__ __forceinline__ float bf2f(u16 h) {
  union { u32 u; float f; } v; v.u = ((u32)h) << 16;
  return v.f;
}
// pack two floats to bf16x2 (round-half-up) in one v_perm
__device__ __forceinline__ u32 pk2bf(float lo, float hi) {
  union { float f; u32 u; } a, b; a.f = lo; b.f = hi;
  return __builtin_amdgcn_perm(b.u + 0x8000u, a.u + 0x8000u, 0x07060302u);
}
__device__ __forceinline__ float fexp2(float x) {
#if __has_builtin(__builtin_amdgcn_exp2f)
  return __builtin_amdgcn_exp2f(x);
#else
  return exp2f(x);
#endif
}

// ---------------- fused prep: rmsnorm + both weight casts (1 launch) ----------
__global__ __launch_bounds__(256) void prep_kernel(const float* __restrict__ x,
                                                   const float* __restrict__ wgt,
                                                   const float* __restrict__ w_qkv,
                                                   const float* __restrict__ w_out,
                                                   u16* __restrict__ h,
                                                   u16* __restrict__ wqkv_b,
                                                   u16* __restrict__ wout_b) {
  __shared__ float red[4];
  const int bid = blockIdx.x, tid = threadIdx.x;
  if (bid < 4096) {
    // RMSNorm row
    const int row = bid;
    const float4 v = *(const float4*)&x[(size_t)row * 1024 + tid * 4];
    float ss = v.x * v.x + v.y * v.y + v.z * v.z + v.w * v.w;
    ss += __shfl_xor(ss, 1);  ss += __shfl_xor(ss, 2);  ss += __shfl_xor(ss, 4);
    ss += __shfl_xor(ss, 8);  ss += __shfl_xor(ss, 16); ss += __shfl_xor(ss, 32);
    if ((tid & 63) == 0) red[tid >> 6] = ss;
    __syncthreads();
    const float tot = red[0] + red[1] + red[2] + red[3];
    const float s = rsqrtf(tot * (1.0f / 1024.0f) + 1e-6f);
    const float4 g = *(const float4*)&wgt[tid * 4];
    uint2 o;
    o.x = (u32)f2bf(v.x * s * g.x) | ((u32)f2bf(v.y * s * g.y) << 16);
    o.y = (u32)f2bf(v.z * s * g.z) | ((u32)f2bf(v.w * s * g.w) << 16);
    *(uint2*)&h[(size_t)row * 1024 + tid * 4] = o;
  } else if (bid < 7168) {
    int i = (bid - 4096) * 256 + tid;          // 786432 float4 of w_qkv
    float4 v = ((const float4*)w_qkv)[i];
    uint2 o;
    o.x = (u32)f2bf(v.x) | ((u32)f2bf(v.y) << 16);
    o.y = (u32)f2bf(v.z) | ((u32)f2bf(v.w) << 16);
    ((uint2*)wqkv_b)[i] = o;
  } else {
    int i = (bid - 7168) * 256 + tid;          // 262144 float4 of w_out
    float4 v = ((const float4*)w_out)[i];
    uint2 o;
    o.x = (u32)f2bf(v.x) | ((u32)f2bf(v.y) << 16);
    o.y = (u32)f2bf(v.z) | ((u32)f2bf(v.w) << 16);
    ((uint2*)wout_b)[i] = o;
  }
}

// ---------------- GEMM 128^2 (kept for out-proj): C = A * Bt^T ----------------
template <int EPI>  // 0: write bf16 C. 1: write fp32 C = acc + resid
__global__ __launch_bounds__(256) void gemm_bt(const u16* __restrict__ A,
                                               const u16* __restrict__ Bt,
                                               u16* __restrict__ Cb,
                                               float* __restrict__ Cf,
                                               const float* __restrict__ resid,
                                               int M, int N, int K) {
  __shared__ __attribute__((aligned(16))) u16 As[128 * 32];
  __shared__ __attribute__((aligned(16))) u16 Bs[128 * 32];
  const int tid = threadIdx.x;
  const int w = tid >> 6, lane = tid & 63;
  const int quad = lane >> 4, l16 = lane & 15;
  const int gm0 = blockIdx.y * 128, gn0 = blockIdx.x * 128;
  const int wm = (w & 1) * 64, wn = (w >> 1) * 64;

  f32x4 acc[4][4] = {};

  for (int k0 = 0; k0 < K; k0 += 32) {
    __syncthreads();
    if (w < 2) {
      #pragma unroll
      for (int i = 0; i < 4; ++i) {
        int sb = (w * 4 + i) * 64;
        int slot = sb + lane;
        int m = slot >> 2, c = (slot & 3) ^ (m & 3);
        GLL16(A + (size_t)(gm0 + m) * K + k0 + c * 8, &As[sb * 8]);
      }
    } else {
      #pragma unroll
      for (int i = 0; i < 4; ++i) {
        int sb = ((w - 2) * 4 + i) * 64;
        int slot = sb + lane;
        int n = slot >> 2, c = (slot & 3) ^ (n & 3);
        GLL16(Bt + (size_t)(gn0 + n) * K + k0 + c * 8, &Bs[sb * 8]);
      }
    }
    __syncthreads();
    s16x8 aF[4], bF[4];
    #pragma unroll
    for (int i = 0; i < 4; ++i) {
      int m = wm + i * 16 + l16;
      aF[i] = *(const s16x8*)&As[(m * 4 + (quad ^ (m & 3))) * 8];
    }
    #pragma unroll
    for (int j = 0; j < 4; ++j) {
      int n = wn + j * 16 + l16;
      bF[j] = *(const s16x8*)&Bs[(n * 4 + (quad ^ (n & 3))) * 8];
    }
    #pragma unroll
    for (int i = 0; i < 4; ++i)
      #pragma unroll
      for (int j = 0; j < 4; ++j)
        acc[i][j] = MFMA16(aF[i], bF[j], acc[i][j]);
  }

  #pragma unroll
  for (int i = 0; i < 4; ++i) {
    int row0 = gm0 + wm + i * 16 + quad * 4;
    #pragma unroll
    for (int j = 0; j < 4; ++j) {
      int col = gn0 + wn + j * 16 + l16;
      #pragma unroll
      for (int r = 0; r < 4; ++r) {
        size_t idx = (size_t)(row0 + r) * N + col;
        if (EPI == 0) Cb[idx] = f2bf(acc[i][j][r]);
        else          Cf[idx] = acc[i][j][r] + resid[idx];
      }
    }
  }
}

// ---------------- GEMM 256^2 v2 (QKV matmul, M=4096 N=3072 K=1024) ------------
// R7 post-mortem: the 4-phase/8-barrier schedule serialized LDS-read drain and
// MFMA per phase (each phase: reads -> barrier -> lgkmcnt(0) -> MFMA -> barrier
// = ~1400 cyc vs ~630 of issue content). v2: 2 barriers per K-tile; all reads
// for the tile issue ahead of their consuming MFMAs (compiler inserts
// fine-grained lgkmcnt - m97 evidence), so the LDS queue drains UNDER the
// matrix pipe (both ~2400 cyc/tile per CU -> overlapped, not summed).
// Hazards: barrier #1 is after all 64 MFMA -> every wave's reads of buf[kt&1]
// have completed (consumed) -> safe to stage B(kt+2) into buf[kt&1].
// A(kt+1) goes to the OTHER buffer (consumed in kt-1) -> safe at tile start.
// vmcnt(4) at tile end: only B(kt+2)'s 4 loads may remain in flight =>
// A(kt+1) and B(kt+1) have landed.  kt=14: vmcnt(0) (no B(16) staged).
__global__ __launch_bounds__(512, 2) void gemm256(const u16* __restrict__ A,
                                                  const u16* __restrict__ Bt,
                                                  u16* __restrict__ Cb) {
  __shared__ __attribute__((aligned(16))) char smem[131072];
  const int tid = threadIdx.x;
  const int w = tid >> 6, lane = tid & 63;
  const int quad = lane >> 4, l16 = lane & 15;
  const int wr = w >> 2, wc = w & 3;
  const int rsw = l16 & 7;
  const int id = blockIdx.x;
  const int sw = (id & 7) * 24 + (id >> 3);    // XCD swizzle, 192 = 8 x 24
  const int by = sw / 12, bx = sw - by * 12;
  const int gm0 = by * 256, gn0 = bx * 256;
  const int scg = (lane & 7) ^ (lane >> 3);    // pre-swizzled src col-group

  // part: 0=A half0, 1=A half1, 2=B half0, 3=B half1 (half = 128 rows)
  auto STAGE_HALF = [&](int kt, int part) {
    const int sb = (kt & 1) * 65536 + (part >> 1) * 32768 + (part & 1) * 16384;
    const u16* src = (part >> 1) ? Bt : A;
    const int g0 = ((part >> 1) ? gn0 : gm0) + (part & 1) * 128;
    const int k0 = kt * 64;
    #pragma unroll
    for (int q = 0; q < 2; ++q) {
      int r = q * 64 + (tid >> 3);
      GLL16(src + (size_t)(g0 + r) * 1024 + k0 + scg * 8,
            smem + sb + q * 8192 + w * 1024);
    }
  };

  f32x4 acc[8][4] = {};

  // prologue: A(0), B(0), B(1).  vmcnt(4): A(0)+B(0) landed, B(1) in flight.
  STAGE_HALF(0, 0); STAGE_HALF(0, 1);
  STAGE_HALF(0, 2); STAGE_HALF(0, 3);
  STAGE_HALF(1, 2); STAGE_HALF(1, 3);
  asm volatile("s_waitcnt vmcnt(4)" ::: "memory");
  __builtin_amdgcn_s_barrier();

  for (int kt = 0; kt < 16; ++kt) {
    const char* Ab = smem + (kt & 1) * 65536;
    const char* Bb = Ab + 32768;
    const int arow = wr * 128 + l16;            // (row&7)==rsw for all frags
    const int brow = wc * 64 + l16;
    s16x8 aA[4][2], bB[4][2];

    // reads: A row-group 0 (8 x b128) + all B (8 x b128)
    #pragma unroll
    for (int fi = 0; fi < 4; ++fi) {
      const char* p = Ab + (arow + fi * 16) * 128;
      aA[fi][0] = *(const s16x8*)(p + ((quad ^ rsw) * 16));
      aA[fi][1] = *(const s16x8*)(p + (((4 + quad) ^ rsw) * 16));
    }
    #pragma unroll
    for (int fj = 0; fj < 4; ++fj) {
      const char* p = Bb + (brow + fj * 16) * 128;
      bB[fj][0] = *(const s16x8*)(p + ((quad ^ rsw) * 16));
      bB[fj][1] = *(const s16x8*)(p + (((4 + quad) ^ rsw) * 16));
    }

    // stage A(kt+1) into the other buffer (its previous content consumed @ kt-1)
    if (kt < 15) { STAGE_HALF(kt + 1, 0); STAGE_HALF(kt + 1, 1); }

    // MFMA row-group 0 x all cols (32) - compiler interleaves lgkmcnt waits
    __builtin_amdgcn_s_setprio(1);
    #pragma unroll
    for (int fi = 0; fi < 4; ++fi)
      #pragma unroll
      for (int fj = 0; fj < 4; ++fj) {
        acc[fi][fj] = MFMA16(aA[fi][0], bB[fj][0], acc[fi][fj]);
        acc[fi][fj] = MFMA16(aA[fi][1], bB[fj][1], acc[fi][fj]);
      }
    __builtin_amdgcn_s_setprio(0);

    // reads: A row-group 1 (8 x b128) - drains under rg0 MFMA execution
    #pragma unroll
    for (int fi = 0; fi < 4; ++fi) {
      const char* p = Ab + (arow + (4 + fi) * 16) * 128;
      aA[fi][0] = *(const s16x8*)(p + ((quad ^ rsw) * 16));
      aA[fi][1] = *(const s16x8*)(p + (((4 + quad) ^ rsw) * 16));
    }

    // MFMA row-group 1 x all cols (32)
    __builtin_amdgcn_s_setprio(1);
    #pragma unroll
    for (int fi = 0; fi < 4; ++fi)
      #pragma unroll
      for (int fj = 0; fj < 4; ++fj) {
        acc[4 + fi][fj] = MFMA16(aA[fi][0], bB[fj][0], acc[4 + fi][fj]);
        acc[4 + fi][fj] = MFMA16(aA[fi][1], bB[fj][1], acc[4 + fi][fj]);
      }
    __builtin_amdgcn_s_setprio(0);

    // all waves' reads of buf[kt&1] complete (consumed by MFMAs above)
    __builtin_amdgcn_s_barrier();

    // stage B(kt+2) into buf[kt&1] B-region (now dead)
    if (kt < 14) {
      STAGE_HALF(kt + 2, 2); STAGE_HALF(kt + 2, 3);
      asm volatile("s_waitcnt vmcnt(4)" ::: "memory");   // A(kt+1),B(kt+1) landed
    } else if (kt == 14) {
      asm volatile("s_waitcnt vmcnt(0)" ::: "memory");   // A(15) landed
    }
    __builtin_amdgcn_s_barrier();
  }

  // epilogue: bf16 C write
  #pragma unroll
  for (int g = 0; g < 8; ++g) {
    const int row0 = gm0 + wr * 128 + g * 16 + quad * 4;
    #pragma unroll
    for (int fj = 0; fj < 4; ++fj) {
      const int col = gn0 + wc * 64 + fj * 16 + l16;
      #pragma unroll
      for (int r = 0; r < 4; ++r)
        Cb[(size_t)(row0 + r) * 3072 + col] = f2bf(acc[g][fj][r]);
    }
  }
}

// ---------------- RoPE + reorder ----------------
// qkv (4096 x 3072) bf16 -> Qr,Kr (bh,T,64), Vt (bh,64,T)
// Q pre-scaled by 0.125*log2(e) so attention uses exp2 directly.
__global__ __launch_bounds__(256) void rope_kernel(const u16* __restrict__ qkv,
                                                   u16* __restrict__ Qr,
                                                   u16* __restrict__ Kr,
                                                   u16* __restrict__ Vt) {
  const int tt = blockIdx.x, bh = blockIdx.y;
  const int b = bh >> 4, h = bh & 15;
  const int tid = threadIdx.x;
  const float QSCALE = 0.125f * 1.4426950408889634f;

  #pragma unroll
  for (int ii = 0; ii < 8; ++ii) {
    int idx = ii * 256 + tid;      // 64 tokens x 32 pairs
    int tl = idx >> 5, jj = idx & 31;
    int t = tt * 64 + tl;
    size_t mrow = (size_t)(b * 2048 + t) * 3072 + h * 64;
    float q1 = bf2f(qkv[mrow + jj]),        q2 = bf2f(qkv[mrow + 32 + jj]);
    float k1 = bf2f(qkv[mrow + 1024 + jj]), k2 = bf2f(qkv[mrow + 1024 + 32 + jj]);
    float invf = exp2f(-(float)jj * (13.287712379549449f / 32.0f));  // 10000^(-j/32)
    float ang = (float)t * invf;
    float sn, cs;
    sincosf(ang, &sn, &cs);
    size_t orow = (size_t)(bh * 2048 + t) * 64;
    Qr[orow + jj]      = f2bf((q1 * cs - q2 * sn) * QSCALE);
    Qr[orow + 32 + jj] = f2bf((q2 * cs + q1 * sn) * QSCALE);
    Kr[orow + jj]      = f2bf(k1 * cs - k2 * sn);
    Kr[orow + 32 + jj] = f2bf(k2 * cs + k1 * sn);
  }

  // V transpose 64x64 via LDS
  __shared__ __attribute__((aligned(16))) u16 Vl[64][72];
  for (int s = tid; s < 512; s += 256) {
    int r = s >> 3, c8 = (s & 7) * 8;
    *(uint4*)&Vl[r][c8] =
        *(const uint4*)&qkv[(size_t)(b * 2048 + tt * 64 + r) * 3072 + 2048 + h * 64 + c8];
  }
  __syncthreads();
  for (int s = tid; s < 512; s += 256) {
    int d = s >> 3, t8 = (s & 7) * 8;
    u16 tmp[8];
    #pragma unroll
    for (int k = 0; k < 8; ++k) tmp[k] = Vl[t8 + k][d];
    *(uint4*)&Vt[(size_t)(bh * 64 + d) * 2048 + tt * 64 + t8] = *(uint4*)tmp;
  }
}

// ---------------- Flash attention v8c (unchanged, passing) -------------------
__global__ __launch_bounds__(512, 2) void attn_kernel(const u16* __restrict__ Qr,
                                                      const u16* __restrict__ Kr,
                                                      const u16* __restrict__ Vt,
                                                      u16* __restrict__ AO) {
  // [0,32K): K[par*2+d][8192]  [32K,64K): V[par*2+d][8192]  [64K,100K): P[8][4608]
  __shared__ __attribute__((aligned(16))) char smem[102400];
  const int tid = threadIdx.x;
  const int w = tid >> 6, lane = tid & 63;
  const int wq = w & 3, wp = w >> 2;          // compute roles: q-quarter, j-parity
  const int quad = lane >> 4, l16 = lane & 15;
  const int id = blockIdx.x;
  const int bh = id & 31;                     // id%8 = bh%8 -> per-bh XCD affinity
  const int c  = id >> 5;                     // pair index 0..7
  const int b = bh >> 4, h = bh & 15;
  const size_t qkb = (size_t)bh * (2048 * 64);
  const size_t vtb = (size_t)bh * (64 * 2048);
  u16* Pw = (u16*)(smem + 65536 + w * 4608);

  const int srow = lane >> 3;                 // row within an 8-row issue
  const int scg  = (lane & 7) ^ srow;         // pre-swizzled 16B col group
  const int smat = w & 1, stp = (w >> 1) & 1, shalf = (w >> 2) & 1;

  auto STAGE = [&](int j0, int d) {
    const int jn = j0 + stp;
    if (smat == 0) {
      #pragma unroll
      for (int ii = 0; ii < 4; ++ii) {
        int i = shalf * 4 + ii;               // 8-row block 0..7
        GLL16(Kr + qkb + (size_t)(jn * 64 + i * 8 + srow) * 64 + scg * 8,
              smem + (stp * 2 + d) * 8192 + i * 1024);
      }
    } else {
      #pragma unroll
      for (int ii = 0; ii < 4; ++ii) {
        int i = shalf * 4 + ii;               // 8 d-rows each
        GLL16(Vt + vtb + (size_t)(i * 8 + srow) * 2048 + jn * 64 + scg * 8,
              smem + 32768 + (stp * 2 + d) * 8192 + i * 1024);
      }
    }
  };

  for (int t = 0; t < 2; ++t) {
    const int qblk = t ? (15 - c) : c;
    const int q0w = qblk * 128 + wq * 32;     // this wave's 32 q-rows
    const int steps = qblk + 1;               // j-tiles = 2*steps (always even)

    s16x8 bQ[2][2];
    #pragma unroll
    for (int s = 0; s < 2; ++s)
      #pragma unroll
      for (int hf = 0; hf < 2; ++hf)
        bQ[s][hf] = *(const s16x8*)&Qr[qkb + (size_t)(q0w + s * 16 + l16) * 64 + hf * 32 + quad * 8];

    f32x4 O[2][4] = {};
    float l_run[2] = {0.0f, 0.0f};

    STAGE(0, 0);
    __syncthreads();

    for (int st = 0; st < steps; ++st) {
      const int cur = st & 1;
      if (st + 1 < steps) STAGE(2 * st + 2, cur ^ 1);

      const int j = 2 * st + wp;
      if (j * 64 <= q0w + 31) {
        const u16* Kb = (const u16*)(smem + (wp * 2 + cur) * 8192);
        const u16* Vb = (const u16*)(smem + 32768 + (wp * 2 + cur) * 8192);
        const bool masked = (j * 64 + 63 > q0w);
        const int rsw = (l16 & 7);

        s16x8 aK[4][2];
        #pragma unroll
        for (int kt = 0; kt < 4; ++kt)
          #pragma unroll
          for (int hf = 0; hf < 2; ++hf)
            aK[kt][hf] = *(const s16x8*)&Kb[(kt * 16 + l16) * 64 + (((hf * 4 + quad) ^ rsw) * 8)];

        f32x4 S[2][4];
        __builtin_amdgcn_s_setprio(1);
        #pragma unroll
        for (int kt = 0; kt < 4; ++kt)
          #pragma unroll
          for (int s = 0; s < 2; ++s) {
            f32x4 z = {};
            z = MFMA16(aK[kt][0], bQ[s][0], z);
            S[s][kt] = MFMA16(aK[kt][1], bQ[s][1], z);
          }
        __builtin_amdgcn_s_setprio(0);

        if (masked) {
          #pragma unroll
          for (int s = 0; s < 2; ++s) {
            int q = q0w + s * 16 + l16;
            #pragma unroll
            for (int kt = 0; kt < 4; ++kt) {
              int key0 = j * 64 + kt * 16 + quad * 4;
              #pragma unroll
              for (int r = 0; r < 4; ++r)
                if (key0 + r > q) S[s][kt][r] = -1e30f;
            }
          }
        }

        #pragma unroll
        for (int s = 0; s < 2; ++s) {
          float sum = 0.0f;
          #pragma unroll
          for (int kt = 0; kt < 4; ++kt) {
            #pragma unroll
            for (int r = 0; r < 4; ++r) {
              float e = fexp2(S[s][kt][r]);
              S[s][kt][r] = e;
              sum += e;
            }
          }
          sum += __shfl_xor(sum, 16);
          sum += __shfl_xor(sum, 32);
          l_run[s] += sum;
          #pragma unroll
          for (int kt = 0; kt < 4; ++kt) {
            uint2 pw;
            pw.x = pk2bf(S[s][kt][0], S[s][kt][1]);
            pw.y = pk2bf(S[s][kt][2], S[s][kt][3]);
            *(uint2*)&Pw[s * 1152 + l16 * 72 + kt * 16 + quad * 4] = pw;
          }
        }

        s16x8 bP[2][2];
        #pragma unroll
        for (int s = 0; s < 2; ++s) {
          bP[s][0] = *(const s16x8*)&Pw[s * 1152 + l16 * 72 + quad * 8];
          bP[s][1] = *(const s16x8*)&Pw[s * 1152 + l16 * 72 + 32 + quad * 8];
        }
        s16x8 aV[4][2];
        #pragma unroll
        for (int dt = 0; dt < 4; ++dt)
          #pragma unroll
          for (int hf = 0; hf < 2; ++hf)
            aV[dt][hf] = *(const s16x8*)&Vb[(dt * 16 + l16) * 64 + (((hf * 4 + quad) ^ rsw) * 8)];

        __builtin_amdgcn_s_setprio(1);
        #pragma unroll
        for (int dt = 0; dt < 4; ++dt)
          #pragma unroll
          for (int s = 0; s < 2; ++s) {
            O[s][dt] = MFMA16(aV[dt][0], bP[s][0], O[s][dt]);
            O[s][dt] = MFMA16(aV[dt][1], bP[s][1], O[s][dt]);
          }
        __builtin_amdgcn_s_setprio(0);
      }

      __syncthreads();
    }

    // ---- parity combine (exact) ----
    if (wp == 1) {
      float* Lsl = (float*)(smem + 65536 + wq * 512);
      Lsl[lane]      = l_run[0];
      Lsl[64 + lane] = l_run[1];
      f32x4* slot = (f32x4*)smem + wq * 512;
      #pragma unroll
      for (int s = 0; s < 2; ++s)
        #pragma unroll
        for (int dt = 0; dt < 4; ++dt)
          slot[(s * 4 + dt) * 64 + lane] = O[s][dt];
    }
    __syncthreads();
    if (wp == 0) {
      const float* Lsl = (const float*)(smem + 65536 + wq * 512);
      const f32x4* slot = (const f32x4*)smem + wq * 512;
      #pragma unroll
      for (int s = 0; s < 2; ++s) {
        float l_tot = l_run[s] + Lsl[s * 64 + lane];
        float inv = __builtin_amdgcn_rcpf(l_tot);
        int q = q0w + s * 16 + l16;
        #pragma unroll
        for (int dt = 0; dt < 4; ++dt) {
          f32x4 o = O[s][dt] + slot[(s * 4 + dt) * 64 + lane];
          uint2 ow;
          ow.x = pk2bf(o[0] * inv, o[1] * inv);
          ow.y = pk2bf(o[2] * inv, o[3] * inv);
          *(uint2*)&AO[(size_t)(b * 2048 + q) * 1024 + h * 64 + dt * 16 + quad * 4] = ow;
        }
      }
    }
    __syncthreads();
  }
}

// ---------------- launcher ----------------
extern "C" void kernel_launch(void* const* d_in, const int* in_sizes, int n_in,
                              void* d_out, int out_size, void* d_ws, size_t ws_size,
                              hipStream_t stream) {
  const float* x      = (const float*)d_in[0];
  const float* norm_w = (const float*)d_in[1];
  const float* w_qkv  = (const float*)d_in[2];
  const float* w_out  = (const float*)d_in[3];
  float* out = (float*)d_out;

  u16* ws     = (u16*)d_ws;
  u16* wqkv_b = ws;                      // 3 145 728
  u16* wout_b = wqkv_b + 3145728;        // 1 048 576
  u16* h_b    = wout_b + 1048576;        // 4 194 304
  u16* qkv_b  = h_b + 4194304;           // 12 582 912
  u16* Qr     = qkv_b + 12582912;        // 4 194 304
  u16* Kr     = Qr + 4194304;            // 4 194 304
  u16* Vt     = Kr + 4194304;            // 4 194 304
  u16* AO     = Vt + 4194304;            // 4 194 304  (total ~75.5 MB)

  prep_kernel<<<8192, 256, 0, stream>>>(x, norm_w, w_qkv, w_out, h_b, wqkv_b, wout_b);
  gemm256<<<192, 512, 0, stream>>>(h_b, wqkv_b, qkv_b);
  rope_kernel<<<dim3(32, 32), 256, 0, stream>>>(qkv_b, Qr, Kr, Vt);
  attn_kernel<<<256, 512, 0, stream>>>(Qr, Kr, Vt, AO);
  gemm_bt<1><<<dim3(8, 32), 256, 0, stream>>>(AO, wout_b, nullptr, out, x,
                                              4096, 1024, 1024);
}